// Round 5
// baseline (740.160 us; speedup 1.0000x reference)
//
#include <hip/hip_runtime.h>
#include <hip/hip_bf16.h>

typedef int  i32x4 __attribute__((ext_vector_type(4)));
typedef unsigned int uint;
typedef unsigned long long u64;

constexpr int TN = 64;
constexpr float W_INV = 1.1920928955078125e-7f;  // 2^-23

// ---------------- ws layout (26.25 MB) ----------------
// [0,16M)    XPk1: k-packed input bits [2048 b][64 t][16 kw] u64  (ACC f32 aliases after K1)
// [16M,24M)  XP2 : k-packed s1 bits    [2048 b][64 t][8 kw] u64
// [24M,+1.5M)  W1 digit tiles [3 comp][4 hb][16 kb][4 kg][128 row][16] i8
// [+1.5M,+2.25M) W2 digit tiles [3][4][8][4][128][16] i8
static constexpr size_t OFF_XP2 = (size_t)16 << 20;
static constexpr size_t OFF_W1  = (size_t)24 << 20;
static constexpr size_t OFF_W2  = OFF_W1 + ((size_t)3 * 4 * 16 * 8192);
static constexpr size_t WS_NEED = OFF_W2 + ((size_t)3 * 4 * 8 * 8192);

// ---------------- P0: bit-transpose-pack X ----------------
__global__ __launch_bounds__(256) void pack_x(const float* __restrict__ X,
                                              u64* __restrict__ XP) {
    __shared__ float L[64 * 65];
    const int kw = blockIdx.x;   // 0..15
    const int b  = blockIdx.y;   // 0..2047
    const int tid = threadIdx.x;
    const float* src = X + (((size_t)b * 1024 + kw * 64) << 6);
#pragma unroll
    for (int i = 0; i < 4; ++i) {
        int flat = tid + i * 256;
        float4 v = ((const float4*)src)[flat];
        int e0 = flat * 4;
        int k = e0 >> 6, t0 = e0 & 63;
        float* d = &L[k * 65 + t0];
        d[0] = v.x; d[1] = v.y; d[2] = v.z; d[3] = v.w;
    }
    __syncthreads();
    const int w = tid >> 6, lane = tid & 63;
    u64 myw = 0;
#pragma unroll
    for (int tt = 0; tt < 16; ++tt) {
        int t = w * 16 + tt;
        bool pred = L[lane * 65 + t] > 0.5f;
        u64 bm = __ballot(pred);
        if (lane == tt) myw = bm;
    }
    if (lane < 16) XP[((size_t)b * 64 + w * 16 + lane) * 16 + kw] = myw;
}

// ---------------- P1: quantize W (scale 2^23), 3-digit balanced base-128 split ----------------
// q = hi*2^14 + mid*2^7 + lo;  mid,lo in [-64,63], |hi| <= 23. Exact.
// dAll layout: [comp][hb][kb][kg][row][16] i8
__global__ __launch_bounds__(256) void pack_w3(const float* __restrict__ W, int kshift, int KB,
                                               char* __restrict__ dAll) {
    int g = blockIdx.x * 256 + threadIdx.x;
    int h = g >> kshift;
    int k = g & ((1 << kshift) - 1);
    float v = W[g];
    int q  = (int)rintf(v * 8388608.f);       // |q| <= 370728
    int lo = ((q + 64) & 127) - 64;
    int q1 = (q - lo) >> 7;
    int mid = ((q1 + 64) & 127) - 64;
    int hi  = (q1 - mid) >> 7;                // |hi| <= 23
    size_t inTile = (size_t)((k & 63) >> 4) * 2048 + (h & 127) * 16 + (k & 15);
    size_t tile0  = (size_t)((h >> 7) * KB + (k >> 6)) * 8192;
    size_t compStride = (size_t)4 * KB * 8192;
    dAll[tile0 + inTile]                  = (char)hi;
    dAll[compStride + tile0 + inTile]     = (char)mid;
    dAll[2 * compStride + tile0 + inTile] = (char)lo;
}

// ---------------- main fused i8-MFMA GEMM + LIF scan ----------------
// 768 thr = 12 waves = (hl digit 0..2) x (wm) x (wn). Tile 128h x 128n, n = b*64+t (2 b's).
// dot = ((hi_acc<<7)+mid_acc)*128 + lo_acc exactly; c = dot * 2^-23 + bias.
template <int KB, bool EMIT>
__global__ __launch_bounds__(768, 3) void spike_mfma_i8(
    const char* __restrict__ dAll,   // [3][4][KB][8192]
    const u64* __restrict__ XPsrc,   // [b][t][KB]
    const float* __restrict__ bias,  // [512]
    u64* __restrict__ XPdst,         // EMIT: [b][t][8]
    float* __restrict__ AccOut)      // !EMIT: [b][512]
{
    __shared__ __align__(16) char smem[65536];
    // GEMM: A0 [0,8K) A1 [8K,16K) A2 [16K,24K) B [24K,32K).
    // Epilogue: Cchm i32 [0,32K), Clo i32 [32K,64K).
    char* ldsB = smem + 24576;
    const int tid = threadIdx.x;
    const int nb = blockIdx.x;   // 0..1023
    const int hb = blockIdx.y;   // 0..3
    const int b0 = nb * 2;
    const int w = tid >> 6, lane = tid & 63;
    const int hl = w >> 2;             // digit component
    const int wm = (w >> 1) & 1, wn = w & 1;

    i32x4 acc[4][4] = {};

    // A staging: 1536 uint4 per kb; thread covers flat = tid and tid+768.
    const uint4* gA = (const uint4*)dAll;
    const int f0 = tid, f1 = tid + 768;
    const int base0 = (((f0 >> 9) * 4 + hb) * KB) * 512 + (f0 & 511);
    const int base1 = (((f1 >> 9) * 4 + hb) * KB) * 512 + (f1 & 511);

    // B unpack assignment (tid < 512): thread -> (n row, k-group)
    const int un = tid >> 2;
    const int kg = tid & 3;
    const u64* usrc = XPsrc + ((size_t)(b0 + ((un >> 6) & 1)) * 64 + (un & 63)) * KB;

    const char* aBase = smem + hl * 8192;
    const int fkg  = (lane >> 4) * 2048;
    const int frow = lane & 15;

    for (int kb = 0; kb < KB; ++kb) {
        uint4 ra0 = gA[base0 + kb * 512];
        uint4 ra1 = gA[base1 + kb * 512];
        u64 wbits = 0;
        if (tid < 512) wbits = usrc[kb];
        __syncthreads();                       // prior iteration's LDS reads done
        *(uint4*)(smem + f0 * 16) = ra0;
        *(uint4*)(smem + f1 * 16) = ra1;
        if (tid < 512) {
            uint bits16 = (uint)(wbits >> (kg * 16)) & 0xFFFFu;
            uint4 wv;
            wv.x = ((bits16 & 15u) * 0x204081u) & 0x01010101u;
            wv.y = (((bits16 >> 4) & 15u) * 0x204081u) & 0x01010101u;
            wv.z = (((bits16 >> 8) & 15u) * 0x204081u) & 0x01010101u;
            wv.w = (((bits16 >> 12) & 15u) * 0x204081u) & 0x01010101u;
            *(uint4*)(ldsB + kg * 2048 + un * 16) = wv;
        }
        __syncthreads();
        i32x4 av[4], bv[4];
#pragma unroll
        for (int mi = 0; mi < 4; ++mi)
            av[mi] = *(const i32x4*)(aBase + fkg + (wm * 64 + mi * 16 + frow) * 16);
#pragma unroll
        for (int ni = 0; ni < 4; ++ni)
            bv[ni] = *(const i32x4*)(ldsB + fkg + (wn * 64 + ni * 16 + frow) * 16);
#pragma unroll
        for (int mi = 0; mi < 4; ++mi)
#pragma unroll
            for (int ni = 0; ni < 4; ++ni)
                acc[mi][ni] = __builtin_amdgcn_mfma_i32_16x16x64_i8(av[mi], bv[ni], acc[mi][ni], 0, 0, 0);
    }
    __syncthreads();

    // ---- epilogue: combine digit waves in LDS, then LIF scan; one b-half per phase ----
    const float bb = bias[hb * 128 + (tid & 127)];
#pragma unroll
    for (int p = 0; p < 2; ++p) {
        if (wn == p && hl != 1) {
            char* reg = smem + (hl == 0 ? 0 : 32768);   // hi -> Cchm, lo -> Clo
            const int sh = (hl == 0) ? 7 : 0;
#pragma unroll
            for (int mi = 0; mi < 4; ++mi)
#pragma unroll
                for (int ni = 0; ni < 4; ++ni) {
                    int t = ni * 16 + (lane & 15);
                    int h = wm * 64 + mi * 16 + ((lane >> 4) << 2);
                    i32x4 v = acc[mi][ni] << sh;
                    *(i32x4*)(reg + t * 512 + ((h * 4) ^ ((t & 7) << 4))) = v;
                }
        }
        __syncthreads();
        if (wn == p && hl == 1) {
#pragma unroll
            for (int mi = 0; mi < 4; ++mi)
#pragma unroll
                for (int ni = 0; ni < 4; ++ni) {
                    int t = ni * 16 + (lane & 15);
                    int h = wm * 64 + mi * 16 + ((lane >> 4) << 2);
                    i32x4* pp = (i32x4*)(smem + t * 512 + ((h * 4) ^ ((t & 7) << 4)));
                    *pp = *pp + acc[mi][ni];
                }
        }
        __syncthreads();
        if (tid < 128) {
            const int b = b0 + p;
            const int h4 = tid * 4;
            float v = 0.f, s = 0.f;
            if constexpr (EMIT) {
                u64 myw = 0;
                for (int t = 0; t < TN; ++t) {
                    int chm = *(const int*)(smem + t * 512 + (h4 ^ ((t & 7) << 4)));
                    int lo  = *(const int*)(smem + 32768 + t * 512 + (h4 ^ ((t & 7) << 4)));
                    float cc = (float)(chm * 128 + lo) * W_INV + bb;
                    v = v * (1.f - s) * 0.75f + cc;
                    bool sp = v > 0.5f;
                    s = sp ? 1.f : 0.f;
                    u64 bm = __ballot(sp);
                    if ((tid & 63) == t) myw = bm;
                }
                XPdst[((size_t)b * 64 + (tid & 63)) * 8 + hb * 2 + (tid >> 6)] = myw;
            } else {
                float a = 0.f;
                for (int t = 0; t < TN; ++t) {
                    int chm = *(const int*)(smem + t * 512 + (h4 ^ ((t & 7) << 4)));
                    int lo  = *(const int*)(smem + 32768 + t * 512 + (h4 ^ ((t & 7) << 4)));
                    float cc = (float)(chm * 128 + lo) * W_INV + bb;
                    v = v * (1.f - s) * 0.75f + cc;
                    bool sp = v > 0.5f;
                    s = sp ? 1.f : 0.f;
                    a += s;
                }
                AccOut[(size_t)b * 512 + hb * 128 + tid] = a;
            }
        }
        __syncthreads();
    }
}

// ---------------- K3: out = ACC @ Wout^T + bout (f32 VALU) ----------------
__global__ __launch_bounds__(256) void k3_gemm(
    const float* __restrict__ A, const float* __restrict__ Wo,
    const float* __restrict__ bq, float* __restrict__ C) {
    __shared__ float Al[64][33];
    __shared__ float Bl[32][65];
    const int n0 = blockIdx.x * 64;
    const int m0 = blockIdx.y * 64;
    const int tid = threadIdx.x;
    const int c0 = (tid & 15) * 4;
    const int r0 = (tid >> 4) * 4;
    float acc[4][4];
#pragma unroll
    for (int i = 0; i < 4; ++i)
#pragma unroll
        for (int j = 0; j < 4; ++j) acc[i][j] = 0.f;
    for (int k0 = 0; k0 < 512; k0 += 32) {
#pragma unroll
        for (int i = 0; i < 2; ++i) {
            int g = tid + 256 * i;
            int row = g >> 3, c4 = g & 7;
            float4 v = *(const float4*)(A + (size_t)(m0 + row) * 512 + k0 + c4 * 4);
            float* d = &Al[row][c4 * 4];
            d[0] = v.x; d[1] = v.y; d[2] = v.z; d[3] = v.w;
        }
#pragma unroll
        for (int i = 0; i < 2; ++i) {
            int g = tid + 256 * i;
            int row = g >> 3, c4 = g & 7;
            float4 v = *(const float4*)(Wo + (size_t)(n0 + row) * 512 + k0 + c4 * 4);
            Bl[c4 * 4 + 0][row] = v.x; Bl[c4 * 4 + 1][row] = v.y;
            Bl[c4 * 4 + 2][row] = v.z; Bl[c4 * 4 + 3][row] = v.w;
        }
        __syncthreads();
#pragma unroll 8
        for (int kk = 0; kk < 32; ++kk) {
            float a0 = Al[r0 + 0][kk], a1 = Al[r0 + 1][kk];
            float a2 = Al[r0 + 2][kk], a3 = Al[r0 + 3][kk];
            float b0 = Bl[kk][c0 + 0], b1 = Bl[kk][c0 + 1];
            float b2 = Bl[kk][c0 + 2], b3 = Bl[kk][c0 + 3];
            acc[0][0] = fmaf(a0, b0, acc[0][0]); acc[0][1] = fmaf(a0, b1, acc[0][1]);
            acc[0][2] = fmaf(a0, b2, acc[0][2]); acc[0][3] = fmaf(a0, b3, acc[0][3]);
            acc[1][0] = fmaf(a1, b0, acc[1][0]); acc[1][1] = fmaf(a1, b1, acc[1][1]);
            acc[1][2] = fmaf(a1, b2, acc[1][2]); acc[1][3] = fmaf(a1, b3, acc[1][3]);
            acc[2][0] = fmaf(a2, b0, acc[2][0]); acc[2][1] = fmaf(a2, b1, acc[2][1]);
            acc[2][2] = fmaf(a2, b2, acc[2][2]); acc[2][3] = fmaf(a2, b3, acc[2][3]);
            acc[3][0] = fmaf(a3, b0, acc[3][0]); acc[3][1] = fmaf(a3, b1, acc[3][1]);
            acc[3][2] = fmaf(a3, b2, acc[3][2]); acc[3][3] = fmaf(a3, b3, acc[3][3]);
        }
        __syncthreads();
    }
#pragma unroll
    for (int i = 0; i < 4; ++i) {
        float4 o = make_float4(acc[i][0] + bq[n0 + c0 + 0], acc[i][1] + bq[n0 + c0 + 1],
                               acc[i][2] + bq[n0 + c0 + 2], acc[i][3] + bq[n0 + c0 + 3]);
        *(float4*)&C[(size_t)(m0 + r0 + i) * 512 + n0 + c0] = o;
    }
}

// ---------------- fallback f32 path (ws too small) ----------------
template <int KDIM, bool PIN>
__global__ __launch_bounds__(256) void gemm_scan(
    const float* __restrict__ Xf, const u64* __restrict__ Xp,
    const float* __restrict__ W, const float* __restrict__ bias,
    u64* __restrict__ Sout, float* __restrict__ AccOut) {
    __shared__ union {
        struct { float Wt[32 * 260]; float Xc[32 * 64]; } s;
        float C[256 * 64];
    } lds;
    const int b = blockIdx.y;
    const int h0 = blockIdx.x * 256;
    const int tid = threadIdx.x;
    const int tc = tid & 3, tr = tid >> 2;
    const int t0 = tc * 16, r0 = tr * 4;
    float c[4][16];
#pragma unroll
    for (int i = 0; i < 4; ++i)
#pragma unroll
        for (int j = 0; j < 16; ++j) c[i][j] = 0.f;
    for (int k0 = 0; k0 < KDIM; k0 += 32) {
        if constexpr (!PIN) {
            const float4* xsrc = (const float4*)(Xf + ((size_t)b * KDIM + k0) * 64);
            float4* xdst = (float4*)lds.s.Xc;
            xdst[tid] = xsrc[tid];
            xdst[tid + 256] = xsrc[tid + 256];
        } else {
            const int row = tid >> 3;
            const int bofs = (tid & 7) * 8;
            u64 m = Xp[(size_t)b * KDIM + k0 + row];
            float* xd = &lds.s.Xc[row * 64 + bofs];
#pragma unroll
            for (int q = 0; q < 8; ++q) xd[q] = (float)((m >> (bofs + q)) & 1ull);
        }
#pragma unroll
        for (int i = 0; i < 8; ++i) {
            int g = tid + 256 * i;
            int row = g >> 3, c4 = g & 7;
            float4 w4 = *(const float4*)(W + (size_t)(h0 + row) * KDIM + k0 + c4 * 4);
            lds.s.Wt[(c4 * 4 + 0) * 260 + row] = w4.x;
            lds.s.Wt[(c4 * 4 + 1) * 260 + row] = w4.y;
            lds.s.Wt[(c4 * 4 + 2) * 260 + row] = w4.z;
            lds.s.Wt[(c4 * 4 + 3) * 260 + row] = w4.w;
        }
        __syncthreads();
#pragma unroll 4
        for (int kk = 0; kk < 32; ++kk) {
            float4 wv = *(const float4*)&lds.s.Wt[kk * 260 + r0];
            const float4* xr = (const float4*)&lds.s.Xc[kk * 64 + t0];
            float4 x0 = xr[0], x1 = xr[1], x2 = xr[2], x3 = xr[3];
            float wr[4] = {wv.x, wv.y, wv.z, wv.w};
            float xs[16] = {x0.x, x0.y, x0.z, x0.w, x1.x, x1.y, x1.z, x1.w,
                            x2.x, x2.y, x2.z, x2.w, x3.x, x3.y, x3.z, x3.w};
#pragma unroll
            for (int i = 0; i < 4; ++i)
#pragma unroll
                for (int j = 0; j < 16; ++j) c[i][j] = fmaf(wr[i], xs[j], c[i][j]);
        }
        __syncthreads();
    }
#pragma unroll
    for (int i = 0; i < 4; ++i)
#pragma unroll
        for (int j4 = 0; j4 < 4; ++j4)
            *(float4*)&lds.C[(r0 + i) * 64 + t0 + j4 * 4] =
                make_float4(c[i][j4 * 4], c[i][j4 * 4 + 1], c[i][j4 * 4 + 2], c[i][j4 * 4 + 3]);
    __syncthreads();
    const float bb = bias[h0 + tid];
    float v = 0.f, s = 0.f;
    if constexpr (!PIN) {
        u64 m = 0;
#pragma unroll
        for (int t = 0; t < TN; ++t) {
            float cc = lds.C[tid * 64 + t] + bb;
            v = v * (1.f - s) * 0.75f + cc;
            bool sp = v > 0.5f;
            s = sp ? 1.f : 0.f;
            if (sp) m |= (1ull << t);
        }
        Sout[(size_t)b * 512 + h0 + tid] = m;
    } else {
        float acc = 0.f;
#pragma unroll
        for (int t = 0; t < TN; ++t) {
            float cc = lds.C[tid * 64 + t] + bb;
            v = v * (1.f - s) * 0.75f + cc;
            bool sp = v > 0.5f;
            s = sp ? 1.f : 0.f;
            acc += s;
        }
        AccOut[(size_t)b * 512 + h0 + tid] = acc;
    }
}

extern "C" void kernel_launch(void* const* d_in, const int* in_sizes, int n_in,
                              void* d_out, int out_size, void* d_ws, size_t ws_size,
                              hipStream_t stream) {
    const float* X  = (const float*)d_in[0];
    const float* W1 = (const float*)d_in[1];
    const float* b1 = (const float*)d_in[2];
    const float* W2 = (const float*)d_in[3];
    const float* b2 = (const float*)d_in[4];
    const float* Wo = (const float*)d_in[5];
    const float* bo = (const float*)d_in[6];
    float* out = (float*)d_out;

    if (ws_size >= WS_NEED) {
        char* ws = (char*)d_ws;
        u64* XPk1 = (u64*)ws;
        u64* XP2  = (u64*)(ws + OFF_XP2);
        char* W1d = ws + OFF_W1;
        char* W2d = ws + OFF_W2;
        float* ACC = (float*)ws;  // aliases XPk1 (dead after K1)

        pack_x<<<dim3(16, 2048), 256, 0, stream>>>(X, XPk1);
        pack_w3<<<dim3(2048), 256, 0, stream>>>(W1, 10, 16, W1d);
        pack_w3<<<dim3(1024), 256, 0, stream>>>(W2, 9, 8, W2d);
        spike_mfma_i8<16, true><<<dim3(1024, 4), 768, 0, stream>>>(W1d, XPk1, b1, XP2, nullptr);
        spike_mfma_i8<8, false><<<dim3(1024, 4), 768, 0, stream>>>(W2d, XP2, b2, nullptr, ACC);
        k3_gemm<<<dim3(8, 32), 256, 0, stream>>>(ACC, Wo, bo, out);
    } else {
        u64* S1 = (u64*)d_ws;
        float* ACC = (float*)((char*)d_ws + (size_t)2048 * 512 * 8);
        gemm_scan<1024, false><<<dim3(2, 2048), 256, 0, stream>>>(X, nullptr, W1, b1, S1, nullptr);
        gemm_scan<512, true><<<dim3(2, 2048), 256, 0, stream>>>(nullptr, S1, W2, b2, nullptr, ACC);
        k3_gemm<<<dim3(8, 32), 256, 0, stream>>>(ACC, Wo, bo, out);
    }
}

// Round 6
// 692.871 us; speedup vs baseline: 1.0683x; 1.0683x over previous
//
#include <hip/hip_runtime.h>
#include <hip/hip_bf16.h>

typedef int  i32x4 __attribute__((ext_vector_type(4)));
typedef unsigned int uint;
typedef unsigned long long u64;

constexpr int TN = 64;
constexpr float W_INV = 1.1920928955078125e-7f;  // 2^-23

// ---------------- ws layout (26.25 MB) ----------------
// [0,16M)    XPk1: k-packed input bits [2048 b][64 t][16 kw] u64  (ACC f32 aliases after K1)
// [16M,24M)  XP2 : k-packed s1 bits    [2048 b][64 t][8 kw] u64
// [24M,+1.5M)  W1 digit tiles [3 comp][4 hb][16 kb][4 kg][128 row][16] i8
// [+1.5M,+2.25M) W2 digit tiles [3][4][8][4][128][16] i8
static constexpr size_t OFF_XP2 = (size_t)16 << 20;
static constexpr size_t OFF_W1  = (size_t)24 << 20;
static constexpr size_t OFF_W2  = OFF_W1 + ((size_t)3 * 4 * 16 * 8192);
static constexpr size_t WS_NEED = OFF_W2 + ((size_t)3 * 4 * 8 * 8192);

// ---------------- P0: bit-transpose-pack X ----------------
__global__ __launch_bounds__(256) void pack_x(const float* __restrict__ X,
                                              u64* __restrict__ XP) {
    __shared__ float L[64 * 65];
    const int kw = blockIdx.x;   // 0..15
    const int b  = blockIdx.y;   // 0..2047
    const int tid = threadIdx.x;
    const float* src = X + (((size_t)b * 1024 + kw * 64) << 6);
#pragma unroll
    for (int i = 0; i < 4; ++i) {
        int flat = tid + i * 256;
        float4 v = ((const float4*)src)[flat];
        int e0 = flat * 4;
        int k = e0 >> 6, t0 = e0 & 63;
        float* d = &L[k * 65 + t0];
        d[0] = v.x; d[1] = v.y; d[2] = v.z; d[3] = v.w;
    }
    __syncthreads();
    const int w = tid >> 6, lane = tid & 63;
    u64 myw = 0;
#pragma unroll
    for (int tt = 0; tt < 16; ++tt) {
        int t = w * 16 + tt;
        bool pred = L[lane * 65 + t] > 0.5f;
        u64 bm = __ballot(pred);
        if (lane == tt) myw = bm;
    }
    if (lane < 16) XP[((size_t)b * 64 + w * 16 + lane) * 16 + kw] = myw;
}

// ---------------- P1: quantize W (scale 2^23), 3-digit balanced base-128 split ----------------
__global__ __launch_bounds__(256) void pack_w3(const float* __restrict__ W, int kshift, int KB,
                                               char* __restrict__ dAll) {
    int g = blockIdx.x * 256 + threadIdx.x;
    int h = g >> kshift;
    int k = g & ((1 << kshift) - 1);
    float v = W[g];
    int q  = (int)rintf(v * 8388608.f);       // |q| <= 370728
    int lo = ((q + 64) & 127) - 64;
    int q1 = (q - lo) >> 7;
    int mid = ((q1 + 64) & 127) - 64;
    int hi  = (q1 - mid) >> 7;                // |hi| <= 23
    size_t inTile = (size_t)((k & 63) >> 4) * 2048 + (h & 127) * 16 + (k & 15);
    size_t tile0  = (size_t)((h >> 7) * KB + (k >> 6)) * 8192;
    size_t compStride = (size_t)4 * KB * 8192;
    dAll[tile0 + inTile]                  = (char)hi;
    dAll[compStride + tile0 + inTile]     = (char)mid;
    dAll[2 * compStride + tile0 + inTile] = (char)lo;
}

// ---------------- main fused i8-MFMA GEMM + LIF scan (pipelined) ----------------
// 768 thr = 12 waves = (hl digit 0..2) x (wm) x (wn). Tile 128h x 128n, n = b*64+t (2 b's).
// Double-buffered LDS (2 x 32KB: A 24K + B 8K); register prefetch of kb+1 during compute of kb;
// one lgkm-only barrier per iter (vmcnt stays in flight across it).
template <int KB, bool EMIT>
__global__ __launch_bounds__(768, 3) void spike_mfma_i8(
    const char* __restrict__ dAll,   // [3][4][KB][8192]
    const u64* __restrict__ XPsrc,   // [b][t][KB]
    const float* __restrict__ bias,  // [512]
    u64* __restrict__ XPdst,         // EMIT: [b][t][8]
    float* __restrict__ AccOut)      // !EMIT: [b][512]
{
    __shared__ __align__(16) char smem[65536];
    const int tid = threadIdx.x;
    const int nb = blockIdx.x;   // 0..1023
    const int hb = blockIdx.y;   // 0..3
    const int b0 = nb * 2;
    const int w = tid >> 6, lane = tid & 63;
    const int hl = w >> 2;             // digit component
    const int wm = (w >> 1) & 1, wn = w & 1;

    i32x4 acc[4][4] = {};

    // A staging: 1536 uint4 per kb; thread covers flat = tid and tid+768.
    const uint4* gA = (const uint4*)dAll;
    const int f0 = tid, f1 = tid + 768;
    const int base0 = (((f0 >> 9) * 4 + hb) * KB) * 512 + (f0 & 511);
    const int base1 = (((f1 >> 9) * 4 + hb) * KB) * 512 + (f1 & 511);

    // B unpack assignment (tid < 512): kg = tid>>7 (conflict-free LDS writes), un = tid&127
    const int un = tid & 127;
    const int kg = tid >> 7;
    const u64* usrc = XPsrc + ((size_t)(b0 + (un >> 6)) * 64 + (un & 63)) * KB;

    const int fkg  = (lane >> 4) * 2048;
    const int frow = lane & 15;
    const int aoff = hl * 8192 + fkg;
    const int arow = (wm * 64 + frow) * 16;
    const int boff = 24576 + fkg;
    const int brow = (wn * 64 + frow) * 16;

    // prologue: load kb=0 into regs
    uint4 ra0 = gA[base0];
    uint4 ra1 = gA[base1];
    u64 wbits = (tid < 512) ? usrc[0] : 0;

    for (int kb = 0; kb < KB; ++kb) {
        char* buf = smem + ((kb & 1) << 15);
        // ---- write staged regs (vmcnt wait here, loads are ~1 iter old) ----
        *(uint4*)(buf + f0 * 16) = ra0;
        *(uint4*)(buf + f1 * 16) = ra1;
        if (tid < 512) {
            uint bits16 = (uint)(wbits >> (kg * 16)) & 0xFFFFu;
            uint4 wv;
            wv.x = ((bits16 & 15u) * 0x204081u) & 0x01010101u;
            wv.y = (((bits16 >> 4) & 15u) * 0x204081u) & 0x01010101u;
            wv.z = (((bits16 >> 8) & 15u) * 0x204081u) & 0x01010101u;
            wv.w = (((bits16 >> 12) & 15u) * 0x204081u) & 0x01010101u;
            *(uint4*)(buf + 24576 + kg * 2048 + un * 16) = wv;
        }
        // ---- prefetch kb+1 (in flight across the barrier + compute) ----
        int kbn = (kb + 1 < KB) ? kb + 1 : KB - 1;
        ra0 = gA[base0 + kbn * 512];
        ra1 = gA[base1 + kbn * 512];
        if (tid < 512) wbits = usrc[kbn];
        // ---- barrier: drain LDS only, keep vmcnt in flight ----
        asm volatile("s_waitcnt lgkmcnt(0)" ::: "memory");
        __builtin_amdgcn_s_barrier();
        // ---- compute ----
        i32x4 av[4], bv[4];
#pragma unroll
        for (int mi = 0; mi < 4; ++mi)
            av[mi] = *(const i32x4*)(buf + aoff + arow + mi * 256);
#pragma unroll
        for (int ni = 0; ni < 4; ++ni)
            bv[ni] = *(const i32x4*)(buf + boff + brow + ni * 256);
        __builtin_amdgcn_s_setprio(1);
#pragma unroll
        for (int mi = 0; mi < 4; ++mi)
#pragma unroll
            for (int ni = 0; ni < 4; ++ni)
                acc[mi][ni] = __builtin_amdgcn_mfma_i32_16x16x64_i8(av[mi], bv[ni], acc[mi][ni], 0, 0, 0);
        __builtin_amdgcn_s_setprio(0);
    }
    __syncthreads();

    // ---- epilogue: combine digit waves in LDS, then LIF scan; one b-half per phase ----
    const float bb = bias[hb * 128 + (tid & 127)];
#pragma unroll
    for (int p = 0; p < 2; ++p) {
        if (wn == p && hl != 1) {
            char* reg = smem + (hl == 0 ? 0 : 32768);   // hi -> Cchm, lo -> Clo
            const int sh = (hl == 0) ? 7 : 0;
#pragma unroll
            for (int mi = 0; mi < 4; ++mi)
#pragma unroll
                for (int ni = 0; ni < 4; ++ni) {
                    int t = ni * 16 + (lane & 15);
                    int h = wm * 64 + mi * 16 + ((lane >> 4) << 2);
                    i32x4 v = acc[mi][ni] << sh;
                    *(i32x4*)(reg + t * 512 + ((h * 4) ^ ((t & 7) << 4))) = v;
                }
        }
        __syncthreads();
        if (wn == p && hl == 1) {
#pragma unroll
            for (int mi = 0; mi < 4; ++mi)
#pragma unroll
                for (int ni = 0; ni < 4; ++ni) {
                    int t = ni * 16 + (lane & 15);
                    int h = wm * 64 + mi * 16 + ((lane >> 4) << 2);
                    i32x4* pp = (i32x4*)(smem + t * 512 + ((h * 4) ^ ((t & 7) << 4)));
                    *pp = *pp + acc[mi][ni];
                }
        }
        __syncthreads();
        if (tid < 128) {
            const int b = b0 + p;
            const int h4 = tid * 4;
            float v = 0.f, s = 0.f;
            if constexpr (EMIT) {
                u64 myw = 0;
                for (int t = 0; t < TN; ++t) {
                    int chm = *(const int*)(smem + t * 512 + (h4 ^ ((t & 7) << 4)));
                    int lo  = *(const int*)(smem + 32768 + t * 512 + (h4 ^ ((t & 7) << 4)));
                    float cc = (float)(chm * 128 + lo) * W_INV + bb;
                    v = v * (1.f - s) * 0.75f + cc;
                    bool sp = v > 0.5f;
                    s = sp ? 1.f : 0.f;
                    u64 bm = __ballot(sp);
                    if ((tid & 63) == t) myw = bm;
                }
                XPdst[((size_t)b * 64 + (tid & 63)) * 8 + hb * 2 + (tid >> 6)] = myw;
            } else {
                float a = 0.f;
                for (int t = 0; t < TN; ++t) {
                    int chm = *(const int*)(smem + t * 512 + (h4 ^ ((t & 7) << 4)));
                    int lo  = *(const int*)(smem + 32768 + t * 512 + (h4 ^ ((t & 7) << 4)));
                    float cc = (float)(chm * 128 + lo) * W_INV + bb;
                    v = v * (1.f - s) * 0.75f + cc;
                    bool sp = v > 0.5f;
                    s = sp ? 1.f : 0.f;
                    a += s;
                }
                AccOut[(size_t)b * 512 + hb * 128 + tid] = a;
            }
        }
        __syncthreads();
    }
}

// ---------------- K3: out = ACC @ Wout^T + bout (f32 VALU) ----------------
__global__ __launch_bounds__(256) void k3_gemm(
    const float* __restrict__ A, const float* __restrict__ Wo,
    const float* __restrict__ bq, float* __restrict__ C) {
    __shared__ float Al[64][33];
    __shared__ float Bl[32][65];
    const int n0 = blockIdx.x * 64;
    const int m0 = blockIdx.y * 64;
    const int tid = threadIdx.x;
    const int c0 = (tid & 15) * 4;
    const int r0 = (tid >> 4) * 4;
    float acc[4][4];
#pragma unroll
    for (int i = 0; i < 4; ++i)
#pragma unroll
        for (int j = 0; j < 4; ++j) acc[i][j] = 0.f;
    for (int k0 = 0; k0 < 512; k0 += 32) {
#pragma unroll
        for (int i = 0; i < 2; ++i) {
            int g = tid + 256 * i;
            int row = g >> 3, c4 = g & 7;
            float4 v = *(const float4*)(A + (size_t)(m0 + row) * 512 + k0 + c4 * 4);
            float* d = &Al[row][c4 * 4];
            d[0] = v.x; d[1] = v.y; d[2] = v.z; d[3] = v.w;
        }
#pragma unroll
        for (int i = 0; i < 2; ++i) {
            int g = tid + 256 * i;
            int row = g >> 3, c4 = g & 7;
            float4 v = *(const float4*)(Wo + (size_t)(n0 + row) * 512 + k0 + c4 * 4);
            Bl[c4 * 4 + 0][row] = v.x; Bl[c4 * 4 + 1][row] = v.y;
            Bl[c4 * 4 + 2][row] = v.z; Bl[c4 * 4 + 3][row] = v.w;
        }
        __syncthreads();
#pragma unroll 8
        for (int kk = 0; kk < 32; ++kk) {
            float a0 = Al[r0 + 0][kk], a1 = Al[r0 + 1][kk];
            float a2 = Al[r0 + 2][kk], a3 = Al[r0 + 3][kk];
            float b0 = Bl[kk][c0 + 0], b1 = Bl[kk][c0 + 1];
            float b2 = Bl[kk][c0 + 2], b3 = Bl[kk][c0 + 3];
            acc[0][0] = fmaf(a0, b0, acc[0][0]); acc[0][1] = fmaf(a0, b1, acc[0][1]);
            acc[0][2] = fmaf(a0, b2, acc[0][2]); acc[0][3] = fmaf(a0, b3, acc[0][3]);
            acc[1][0] = fmaf(a1, b0, acc[1][0]); acc[1][1] = fmaf(a1, b1, acc[1][1]);
            acc[1][2] = fmaf(a1, b2, acc[1][2]); acc[1][3] = fmaf(a1, b3, acc[1][3]);
            acc[2][0] = fmaf(a2, b0, acc[2][0]); acc[2][1] = fmaf(a2, b1, acc[2][1]);
            acc[2][2] = fmaf(a2, b2, acc[2][2]); acc[2][3] = fmaf(a2, b3, acc[2][3]);
            acc[3][0] = fmaf(a3, b0, acc[3][0]); acc[3][1] = fmaf(a3, b1, acc[3][1]);
            acc[3][2] = fmaf(a3, b2, acc[3][2]); acc[3][3] = fmaf(a3, b3, acc[3][3]);
        }
        __syncthreads();
    }
#pragma unroll
    for (int i = 0; i < 4; ++i) {
        float4 o = make_float4(acc[i][0] + bq[n0 + c0 + 0], acc[i][1] + bq[n0 + c0 + 1],
                               acc[i][2] + bq[n0 + c0 + 2], acc[i][3] + bq[n0 + c0 + 3]);
        *(float4*)&C[(size_t)(m0 + r0 + i) * 512 + n0 + c0] = o;
    }
}

// ---------------- fallback f32 path (ws too small) ----------------
template <int KDIM, bool PIN>
__global__ __launch_bounds__(256) void gemm_scan(
    const float* __restrict__ Xf, const u64* __restrict__ Xp,
    const float* __restrict__ W, const float* __restrict__ bias,
    u64* __restrict__ Sout, float* __restrict__ AccOut) {
    __shared__ union {
        struct { float Wt[32 * 260]; float Xc[32 * 64]; } s;
        float C[256 * 64];
    } lds;
    const int b = blockIdx.y;
    const int h0 = blockIdx.x * 256;
    const int tid = threadIdx.x;
    const int tc = tid & 3, tr = tid >> 2;
    const int t0 = tc * 16, r0 = tr * 4;
    float c[4][16];
#pragma unroll
    for (int i = 0; i < 4; ++i)
#pragma unroll
        for (int j = 0; j < 16; ++j) c[i][j] = 0.f;
    for (int k0 = 0; k0 < KDIM; k0 += 32) {
        if constexpr (!PIN) {
            const float4* xsrc = (const float4*)(Xf + ((size_t)b * KDIM + k0) * 64);
            float4* xdst = (float4*)lds.s.Xc;
            xdst[tid] = xsrc[tid];
            xdst[tid + 256] = xsrc[tid + 256];
        } else {
            const int row = tid >> 3;
            const int bofs = (tid & 7) * 8;
            u64 m = Xp[(size_t)b * KDIM + k0 + row];
            float* xd = &lds.s.Xc[row * 64 + bofs];
#pragma unroll
            for (int q = 0; q < 8; ++q) xd[q] = (float)((m >> (bofs + q)) & 1ull);
        }
#pragma unroll
        for (int i = 0; i < 8; ++i) {
            int g = tid + 256 * i;
            int row = g >> 3, c4 = g & 7;
            float4 w4 = *(const float4*)(W + (size_t)(h0 + row) * KDIM + k0 + c4 * 4);
            lds.s.Wt[(c4 * 4 + 0) * 260 + row] = w4.x;
            lds.s.Wt[(c4 * 4 + 1) * 260 + row] = w4.y;
            lds.s.Wt[(c4 * 4 + 2) * 260 + row] = w4.z;
            lds.s.Wt[(c4 * 4 + 3) * 260 + row] = w4.w;
        }
        __syncthreads();
#pragma unroll 4
        for (int kk = 0; kk < 32; ++kk) {
            float4 wv = *(const float4*)&lds.s.Wt[kk * 260 + r0];
            const float4* xr = (const float4*)&lds.s.Xc[kk * 64 + t0];
            float4 x0 = xr[0], x1 = xr[1], x2 = xr[2], x3 = xr[3];
            float wr[4] = {wv.x, wv.y, wv.z, wv.w};
            float xs[16] = {x0.x, x0.y, x0.z, x0.w, x1.x, x1.y, x1.z, x1.w,
                            x2.x, x2.y, x2.z, x2.w, x3.x, x3.y, x3.z, x3.w};
#pragma unroll
            for (int i = 0; i < 4; ++i)
#pragma unroll
                for (int j = 0; j < 16; ++j) c[i][j] = fmaf(wr[i], xs[j], c[i][j]);
        }
        __syncthreads();
    }
#pragma unroll
    for (int i = 0; i < 4; ++i)
#pragma unroll
        for (int j4 = 0; j4 < 4; ++j4)
            *(float4*)&lds.C[(r0 + i) * 64 + t0 + j4 * 4] =
                make_float4(c[i][j4 * 4], c[i][j4 * 4 + 1], c[i][j4 * 4 + 2], c[i][j4 * 4 + 3]);
    __syncthreads();
    const float bb = bias[h0 + tid];
    float v = 0.f, s = 0.f;
    if constexpr (!PIN) {
        u64 m = 0;
#pragma unroll
        for (int t = 0; t < TN; ++t) {
            float cc = lds.C[tid * 64 + t] + bb;
            v = v * (1.f - s) * 0.75f + cc;
            bool sp = v > 0.5f;
            s = sp ? 1.f : 0.f;
            if (sp) m |= (1ull << t);
        }
        Sout[(size_t)b * 512 + h0 + tid] = m;
    } else {
        float acc = 0.f;
#pragma unroll
        for (int t = 0; t < TN; ++t) {
            float cc = lds.C[tid * 64 + t] + bb;
            v = v * (1.f - s) * 0.75f + cc;
            bool sp = v > 0.5f;
            s = sp ? 1.f : 0.f;
            acc += s;
        }
        AccOut[(size_t)b * 512 + h0 + tid] = acc;
    }
}

extern "C" void kernel_launch(void* const* d_in, const int* in_sizes, int n_in,
                              void* d_out, int out_size, void* d_ws, size_t ws_size,
                              hipStream_t stream) {
    const float* X  = (const float*)d_in[0];
    const float* W1 = (const float*)d_in[1];
    const float* b1 = (const float*)d_in[2];
    const float* W2 = (const float*)d_in[3];
    const float* b2 = (const float*)d_in[4];
    const float* Wo = (const float*)d_in[5];
    const float* bo = (const float*)d_in[6];
    float* out = (float*)d_out;

    if (ws_size >= WS_NEED) {
        char* ws = (char*)d_ws;
        u64* XPk1 = (u64*)ws;
        u64* XP2  = (u64*)(ws + OFF_XP2);
        char* W1d = ws + OFF_W1;
        char* W2d = ws + OFF_W2;
        float* ACC = (float*)ws;  // aliases XPk1 (dead after K1)

        pack_x<<<dim3(16, 2048), 256, 0, stream>>>(X, XPk1);
        pack_w3<<<dim3(2048), 256, 0, stream>>>(W1, 10, 16, W1d);
        pack_w3<<<dim3(1024), 256, 0, stream>>>(W2, 9, 8, W2d);
        spike_mfma_i8<16, true><<<dim3(1024, 4), 768, 0, stream>>>(W1d, XPk1, b1, XP2, nullptr);
        spike_mfma_i8<8, false><<<dim3(1024, 4), 768, 0, stream>>>(W2d, XP2, b2, nullptr, ACC);
        k3_gemm<<<dim3(8, 32), 256, 0, stream>>>(ACC, Wo, bo, out);
    } else {
        u64* S1 = (u64*)d_ws;
        float* ACC = (float*)((char*)d_ws + (size_t)2048 * 512 * 8);
        gemm_scan<1024, false><<<dim3(2, 2048), 256, 0, stream>>>(X, nullptr, W1, b1, S1, nullptr);
        gemm_scan<512, true><<<dim3(2, 2048), 256, 0, stream>>>(nullptr, S1, W2, b2, nullptr, ACC);
        k3_gemm<<<dim3(8, 32), 256, 0, stream>>>(ACC, Wo, bo, out);
    }
}

// Round 7
// 615.441 us; speedup vs baseline: 1.2026x; 1.1258x over previous
//
#include <hip/hip_runtime.h>
#include <hip/hip_bf16.h>

typedef int  i32x4 __attribute__((ext_vector_type(4)));
typedef unsigned int uint;
typedef unsigned long long u64;

constexpr int TN = 64;
constexpr float W_INV = 1.1920928955078125e-7f;  // 2^-23

// ---------------- ws layout (26.25 MB) ----------------
// [0,16M)    XPk1: k-packed input bits [2048 b][16 kb][64 t] u64  (ACC f32 aliases after K1)
// [16M,24M)  XP2 : k-packed s1 bits    [2048 b][8 kb][64 t] u64
// [24M,+1.5M)   W1 digit tiles [3 comp][4 hb][16 kb][128 row][64 k] i8
// [+1.5M,+2.25M) W2 digit tiles [3][4][8][128][64] i8
static constexpr size_t OFF_XP2 = (size_t)16 << 20;
static constexpr size_t OFF_W1  = (size_t)24 << 20;
static constexpr size_t OFF_W2  = OFF_W1 + ((size_t)3 * 4 * 16 * 8192);
static constexpr size_t WS_NEED = OFF_W2 + ((size_t)3 * 4 * 8 * 8192);

// ---------------- P0: bit-transpose-pack X  -> XP[b][kb][t] ----------------
__global__ __launch_bounds__(256) void pack_x(const float* __restrict__ X,
                                              u64* __restrict__ XP) {
    __shared__ float L[64 * 65];
    const int kw = blockIdx.x;   // 0..15 (kb)
    const int b  = blockIdx.y;   // 0..2047
    const int tid = threadIdx.x;
    const float* src = X + (((size_t)b * 1024 + kw * 64) << 6);
#pragma unroll
    for (int i = 0; i < 4; ++i) {
        int flat = tid + i * 256;
        float4 v = ((const float4*)src)[flat];
        int e0 = flat * 4;
        int k = e0 >> 6, t0 = e0 & 63;
        float* d = &L[k * 65 + t0];
        d[0] = v.x; d[1] = v.y; d[2] = v.z; d[3] = v.w;
    }
    __syncthreads();
    const int w = tid >> 6, lane = tid & 63;
    u64 myw = 0;
#pragma unroll
    for (int tt = 0; tt < 16; ++tt) {
        int t = w * 16 + tt;
        bool pred = L[lane * 65 + t] > 0.5f;   // lane indexes k
        u64 bm = __ballot(pred);
        if (lane == tt) myw = bm;              // lane tt holds word of t=w*16+tt
    }
    if (lane < 16) XP[((size_t)b * 16 + kw) * 64 + w * 16 + lane] = myw;
}

// ---------------- P1: quantize W (scale 2^23), 3-digit balanced base-128 split ----------------
// layout: [comp][hb][kb][row 0..127][k 0..63] i8 (plain row-major 8KB tiles)
__global__ __launch_bounds__(256) void pack_w3(const float* __restrict__ W, int kshift, int KB,
                                               char* __restrict__ dAll) {
    int g = blockIdx.x * 256 + threadIdx.x;
    int h = g >> kshift;
    int k = g & ((1 << kshift) - 1);
    float v = W[g];
    int q  = (int)rintf(v * 8388608.f);       // |q| <= 370728
    int lo = ((q + 64) & 127) - 64;
    int q1 = (q - lo) >> 7;
    int mid = ((q1 + 64) & 127) - 64;
    int hi  = (q1 - mid) >> 7;                // |hi| <= 23
    size_t tile0 = (size_t)((h >> 7) * KB + (k >> 6)) * 8192;
    size_t inT   = (size_t)(h & 127) * 64 + (k & 63);
    size_t compStride = (size_t)4 * KB * 8192;
    dAll[tile0 + inT]                  = (char)hi;
    dAll[compStride + tile0 + inT]     = (char)mid;
    dAll[2 * compStride + tile0 + inT] = (char)lo;
}

// ---------------- main fused i8-MFMA GEMM + LIF scan (barrier-free K-loop) ----------------
// 768 thr = 12 waves = digit(3) x wm(4). Block tile 128h x 128n, n = b*64+t (2 b's).
// Per wave: 32h x 128n, acc[2][8], A loaded per-lane from global (fragment-order pack),
// B expanded in registers from spike bits. LDS + barriers only in the epilogue.
template <int KB, bool EMIT>
__global__ __launch_bounds__(768, 3) void spike_mfma_i8(
    const char* __restrict__ dAll,   // [3][4][KB][128][64]
    const u64* __restrict__ XPsrc,   // [b][KB][64]
    const float* __restrict__ bias,  // [512]
    u64* __restrict__ XPdst,         // EMIT: [b][8][64]
    float* __restrict__ AccOut)      // !EMIT: [b][512]
{
    __shared__ __align__(16) int Cs[128 * 128];   // [n][h] i32, xor-swizzled, 64KB
    const int tid = threadIdx.x;
    const int nb = blockIdx.x;   // 0..1023
    const int hb = blockIdx.y;   // 0..3
    const int b0 = nb * 2;
    const int w = tid >> 6, lane = tid & 63;
    const int hl = w >> 2;          // digit 0..2
    const int wm = w & 3;           // 32-row strip
    const int l15 = lane & 15, lg = lane >> 4;

    i32x4 acc[2][8] = {};

    // A base: fragment-order direct load
    const char* aBase = dAll + ((size_t)(hl * 4 + hb) * KB) * 8192
                        + (wm * 32) * 64 + l15 * 64 + lg * 16;
    // B base: lane l15 picks t within 16-col group
    const u64* bBase = XPsrc + ((size_t)b0 * KB) * 64 + l15;

    // prologue: kb=0
    uint4 a0 = *(const uint4*)(aBase);
    uint4 a1 = *(const uint4*)(aBase + 1024);
    u64 wb[8];
#pragma unroll
    for (int ni = 0; ni < 8; ++ni)
        wb[ni] = bBase[(size_t)((ni >> 2) * KB) * 64 + (ni & 3) * 16];

    const uint sh = lg * 16;
    for (int kb = 0; kb < KB; ++kb) {
        // prefetch kb+1 (stays in flight during compute)
        const int kbn = (kb + 1 < KB) ? kb + 1 : kb;
        uint4 a0n = *(const uint4*)(aBase + (size_t)kbn * 8192);
        uint4 a1n = *(const uint4*)(aBase + (size_t)kbn * 8192 + 1024);
        u64 wbn[8];
#pragma unroll
        for (int ni = 0; ni < 8; ++ni)
            wbn[ni] = bBase[((size_t)(ni >> 2) * KB + kbn) * 64 + (ni & 3) * 16];
        // compute
        i32x4 av0 = __builtin_bit_cast(i32x4, a0);
        i32x4 av1 = __builtin_bit_cast(i32x4, a1);
#pragma unroll
        for (int ni = 0; ni < 8; ++ni) {
            uint field = (uint)(wb[ni] >> sh) & 0xFFFFu;
            i32x4 bf;
            bf[0] = (int)(((field      ) & 15u) * 0x204081u & 0x01010101u);
            bf[1] = (int)(((field >>  4) & 15u) * 0x204081u & 0x01010101u);
            bf[2] = (int)(((field >>  8) & 15u) * 0x204081u & 0x01010101u);
            bf[3] = (int)(((field >> 12) & 15u) * 0x204081u & 0x01010101u);
            acc[0][ni] = __builtin_amdgcn_mfma_i32_16x16x64_i8(av0, bf, acc[0][ni], 0, 0, 0);
            acc[1][ni] = __builtin_amdgcn_mfma_i32_16x16x64_i8(av1, bf, acc[1][ni], 0, 0, 0);
        }
        a0 = a0n; a1 = a1n;
#pragma unroll
        for (int ni = 0; ni < 8; ++ni) wb[ni] = wbn[ni];
    }

    // ---- epilogue: digit combine into Cs[n][h] (xor swizzle), then LIF scan ----
    // C/D frag: n = ni*16 + l15, h = wm*32 + mi*16 + lg*4 + r
    if (hl == 0) {
#pragma unroll
        for (int mi = 0; mi < 2; ++mi)
#pragma unroll
            for (int ni = 0; ni < 8; ++ni) {
                int n = ni * 16 + l15;
                int h4 = (wm * 32 + mi * 16 + lg * 4) * 4;
                *(i32x4*)((char*)Cs + n * 512 + (h4 ^ ((n & 7) << 4))) = acc[mi][ni] << 14;
            }
    }
    __syncthreads();
    if (hl == 1) {
#pragma unroll
        for (int mi = 0; mi < 2; ++mi)
#pragma unroll
            for (int ni = 0; ni < 8; ++ni) {
                int n = ni * 16 + l15;
                int h4 = (wm * 32 + mi * 16 + lg * 4) * 4;
                i32x4* pp = (i32x4*)((char*)Cs + n * 512 + (h4 ^ ((n & 7) << 4)));
                *pp = *pp + (acc[mi][ni] << 7);
            }
    }
    __syncthreads();
    if (hl == 2) {
#pragma unroll
        for (int mi = 0; mi < 2; ++mi)
#pragma unroll
            for (int ni = 0; ni < 8; ++ni) {
                int n = ni * 16 + l15;
                int h4 = (wm * 32 + mi * 16 + lg * 4) * 4;
                i32x4* pp = (i32x4*)((char*)Cs + n * 512 + (h4 ^ ((n & 7) << 4)));
                *pp = *pp + acc[mi][ni];
            }
    }
    __syncthreads();

    if (tid < 256) {
        const int h = tid & 127;
        const int bl = tid >> 7;
        const float bb = bias[hb * 128 + h];
        const char* base = (const char*)Cs + bl * 64 * 512;
        float v = 0.f, s = 0.f;
        if constexpr (EMIT) {
            u64 myw = 0;
            for (int t = 0; t < TN; ++t) {
                int cw = *(const int*)(base + t * 512 + ((h * 4) ^ ((t & 7) << 4)));
                float cc = (float)cw * W_INV + bb;
                v = v * (1.f - s) * 0.75f + cc;
                bool sp = v > 0.5f;
                s = sp ? 1.f : 0.f;
                u64 bm = __ballot(sp);      // bit l = spike of h = (h&64-block) + l
                if ((tid & 63) == t) myw = bm;
            }
            XPdst[(((size_t)(b0 + bl)) * 8 + hb * 2 + (h >> 6)) * 64 + (tid & 63)] = myw;
        } else {
            float a = 0.f;
            for (int t = 0; t < TN; ++t) {
                int cw = *(const int*)(base + t * 512 + ((h * 4) ^ ((t & 7) << 4)));
                float cc = (float)cw * W_INV + bb;
                v = v * (1.f - s) * 0.75f + cc;
                bool sp = v > 0.5f;
                s = sp ? 1.f : 0.f;
                a += s;
            }
            AccOut[(size_t)(b0 + bl) * 512 + hb * 128 + h] = a;
        }
    }
}

// ---------------- K3: out = ACC @ Wout^T + bout (f32 VALU) ----------------
__global__ __launch_bounds__(256) void k3_gemm(
    const float* __restrict__ A, const float* __restrict__ Wo,
    const float* __restrict__ bq, float* __restrict__ C) {
    __shared__ float Al[64][33];
    __shared__ float Bl[32][65];
    const int n0 = blockIdx.x * 64;
    const int m0 = blockIdx.y * 64;
    const int tid = threadIdx.x;
    const int c0 = (tid & 15) * 4;
    const int r0 = (tid >> 4) * 4;
    float acc[4][4];
#pragma unroll
    for (int i = 0; i < 4; ++i)
#pragma unroll
        for (int j = 0; j < 4; ++j) acc[i][j] = 0.f;
    for (int k0 = 0; k0 < 512; k0 += 32) {
#pragma unroll
        for (int i = 0; i < 2; ++i) {
            int g = tid + 256 * i;
            int row = g >> 3, c4 = g & 7;
            float4 v = *(const float4*)(A + (size_t)(m0 + row) * 512 + k0 + c4 * 4);
            float* d = &Al[row][c4 * 4];
            d[0] = v.x; d[1] = v.y; d[2] = v.z; d[3] = v.w;
        }
#pragma unroll
        for (int i = 0; i < 2; ++i) {
            int g = tid + 256 * i;
            int row = g >> 3, c4 = g & 7;
            float4 v = *(const float4*)(Wo + (size_t)(n0 + row) * 512 + k0 + c4 * 4);
            Bl[c4 * 4 + 0][row] = v.x; Bl[c4 * 4 + 1][row] = v.y;
            Bl[c4 * 4 + 2][row] = v.z; Bl[c4 * 4 + 3][row] = v.w;
        }
        __syncthreads();
#pragma unroll 8
        for (int kk = 0; kk < 32; ++kk) {
            float a0 = Al[r0 + 0][kk], a1 = Al[r0 + 1][kk];
            float a2 = Al[r0 + 2][kk], a3 = Al[r0 + 3][kk];
            float b0 = Bl[kk][c0 + 0], b1 = Bl[kk][c0 + 1];
            float b2 = Bl[kk][c0 + 2], b3 = Bl[kk][c0 + 3];
            acc[0][0] = fmaf(a0, b0, acc[0][0]); acc[0][1] = fmaf(a0, b1, acc[0][1]);
            acc[0][2] = fmaf(a0, b2, acc[0][2]); acc[0][3] = fmaf(a0, b3, acc[0][3]);
            acc[1][0] = fmaf(a1, b0, acc[1][0]); acc[1][1] = fmaf(a1, b1, acc[1][1]);
            acc[1][2] = fmaf(a1, b2, acc[1][2]); acc[1][3] = fmaf(a1, b3, acc[1][3]);
            acc[2][0] = fmaf(a2, b0, acc[2][0]); acc[2][1] = fmaf(a2, b1, acc[2][1]);
            acc[2][2] = fmaf(a2, b2, acc[2][2]); acc[2][3] = fmaf(a2, b3, acc[2][3]);
            acc[3][0] = fmaf(a3, b0, acc[3][0]); acc[3][1] = fmaf(a3, b1, acc[3][1]);
            acc[3][2] = fmaf(a3, b2, acc[3][2]); acc[3][3] = fmaf(a3, b3, acc[3][3]);
        }
        __syncthreads();
    }
#pragma unroll
    for (int i = 0; i < 4; ++i) {
        float4 o = make_float4(acc[i][0] + bq[n0 + c0 + 0], acc[i][1] + bq[n0 + c0 + 1],
                               acc[i][2] + bq[n0 + c0 + 2], acc[i][3] + bq[n0 + c0 + 3]);
        *(float4*)&C[(size_t)(m0 + r0 + i) * 512 + n0 + c0] = o;
    }
}

// ---------------- fallback f32 path (ws too small) ----------------
template <int KDIM, bool PIN>
__global__ __launch_bounds__(256) void gemm_scan(
    const float* __restrict__ Xf, const u64* __restrict__ Xp,
    const float* __restrict__ W, const float* __restrict__ bias,
    u64* __restrict__ Sout, float* __restrict__ AccOut) {
    __shared__ union {
        struct { float Wt[32 * 260]; float Xc[32 * 64]; } s;
        float C[256 * 64];
    } lds;
    const int b = blockIdx.y;
    const int h0 = blockIdx.x * 256;
    const int tid = threadIdx.x;
    const int tc = tid & 3, tr = tid >> 2;
    const int t0 = tc * 16, r0 = tr * 4;
    float c[4][16];
#pragma unroll
    for (int i = 0; i < 4; ++i)
#pragma unroll
        for (int j = 0; j < 16; ++j) c[i][j] = 0.f;
    for (int k0 = 0; k0 < KDIM; k0 += 32) {
        if constexpr (!PIN) {
            const float4* xsrc = (const float4*)(Xf + ((size_t)b * KDIM + k0) * 64);
            float4* xdst = (float4*)lds.s.Xc;
            xdst[tid] = xsrc[tid];
            xdst[tid + 256] = xsrc[tid + 256];
        } else {
            const int row = tid >> 3;
            const int bofs = (tid & 7) * 8;
            u64 m = Xp[(size_t)b * KDIM + k0 + row];
            float* xd = &lds.s.Xc[row * 64 + bofs];
#pragma unroll
            for (int q = 0; q < 8; ++q) xd[q] = (float)((m >> (bofs + q)) & 1ull);
        }
#pragma unroll
        for (int i = 0; i < 8; ++i) {
            int g = tid + 256 * i;
            int row = g >> 3, c4 = g & 7;
            float4 w4 = *(const float4*)(W + (size_t)(h0 + row) * KDIM + k0 + c4 * 4);
            lds.s.Wt[(c4 * 4 + 0) * 260 + row] = w4.x;
            lds.s.Wt[(c4 * 4 + 1) * 260 + row] = w4.y;
            lds.s.Wt[(c4 * 4 + 2) * 260 + row] = w4.z;
            lds.s.Wt[(c4 * 4 + 3) * 260 + row] = w4.w;
        }
        __syncthreads();
#pragma unroll 4
        for (int kk = 0; kk < 32; ++kk) {
            float4 wv = *(const float4*)&lds.s.Wt[kk * 260 + r0];
            const float4* xr = (const float4*)&lds.s.Xc[kk * 64 + t0];
            float4 x0 = xr[0], x1 = xr[1], x2 = xr[2], x3 = xr[3];
            float wr[4] = {wv.x, wv.y, wv.z, wv.w};
            float xs[16] = {x0.x, x0.y, x0.z, x0.w, x1.x, x1.y, x1.z, x1.w,
                            x2.x, x2.y, x2.z, x2.w, x3.x, x3.y, x3.z, x3.w};
#pragma unroll
            for (int i = 0; i < 4; ++i)
#pragma unroll
                for (int j = 0; j < 16; ++j) c[i][j] = fmaf(wr[i], xs[j], c[i][j]);
        }
        __syncthreads();
    }
#pragma unroll
    for (int i = 0; i < 4; ++i)
#pragma unroll
        for (int j4 = 0; j4 < 4; ++j4)
            *(float4*)&lds.C[(r0 + i) * 64 + t0 + j4 * 4] =
                make_float4(c[i][j4 * 4], c[i][j4 * 4 + 1], c[i][j4 * 4 + 2], c[i][j4 * 4 + 3]);
    __syncthreads();
    const float bb = bias[h0 + tid];
    float v = 0.f, s = 0.f;
    if constexpr (!PIN) {
        u64 m = 0;
#pragma unroll
        for (int t = 0; t < TN; ++t) {
            float cc = lds.C[tid * 64 + t] + bb;
            v = v * (1.f - s) * 0.75f + cc;
            bool sp = v > 0.5f;
            s = sp ? 1.f : 0.f;
            if (sp) m |= (1ull << t);
        }
        Sout[(size_t)b * 512 + h0 + tid] = m;
    } else {
        float acc = 0.f;
#pragma unroll
        for (int t = 0; t < TN; ++t) {
            float cc = lds.C[tid * 64 + t] + bb;
            v = v * (1.f - s) * 0.75f + cc;
            bool sp = v > 0.5f;
            s = sp ? 1.f : 0.f;
            acc += s;
        }
        AccOut[(size_t)b * 512 + h0 + tid] = acc;
    }
}

extern "C" void kernel_launch(void* const* d_in, const int* in_sizes, int n_in,
                              void* d_out, int out_size, void* d_ws, size_t ws_size,
                              hipStream_t stream) {
    const float* X  = (const float*)d_in[0];
    const float* W1 = (const float*)d_in[1];
    const float* b1 = (const float*)d_in[2];
    const float* W2 = (const float*)d_in[3];
    const float* b2 = (const float*)d_in[4];
    const float* Wo = (const float*)d_in[5];
    const float* bo = (const float*)d_in[6];
    float* out = (float*)d_out;

    if (ws_size >= WS_NEED) {
        char* ws = (char*)d_ws;
        u64* XPk1 = (u64*)ws;
        u64* XP2  = (u64*)(ws + OFF_XP2);
        char* W1d = ws + OFF_W1;
        char* W2d = ws + OFF_W2;
        float* ACC = (float*)ws;  // aliases XPk1 (dead after K1)

        pack_x<<<dim3(16, 2048), 256, 0, stream>>>(X, XPk1);
        pack_w3<<<dim3(2048), 256, 0, stream>>>(W1, 10, 16, W1d);
        pack_w3<<<dim3(1024), 256, 0, stream>>>(W2, 9, 8, W2d);
        spike_mfma_i8<16, true><<<dim3(1024, 4), 768, 0, stream>>>(W1d, XPk1, b1, XP2, nullptr);
        spike_mfma_i8<8, false><<<dim3(1024, 4), 768, 0, stream>>>(W2d, XP2, b2, nullptr, ACC);
        k3_gemm<<<dim3(8, 32), 256, 0, stream>>>(ACC, Wo, bo, out);
    } else {
        u64* S1 = (u64*)d_ws;
        float* ACC = (float*)((char*)d_ws + (size_t)2048 * 512 * 8);
        gemm_scan<1024, false><<<dim3(2, 2048), 256, 0, stream>>>(X, nullptr, W1, b1, S1, nullptr);
        gemm_scan<512, true><<<dim3(2, 2048), 256, 0, stream>>>(nullptr, S1, W2, b2, nullptr, ACC);
        k3_gemm<<<dim3(8, 32), 256, 0, stream>>>(ACC, Wo, bo, out);
    }
}

// Round 8
// 504.474 us; speedup vs baseline: 1.4672x; 1.2200x over previous
//
#include <hip/hip_runtime.h>
#include <hip/hip_bf16.h>
#include <type_traits>

typedef int  i32x4 __attribute__((ext_vector_type(4)));
typedef unsigned int uint;
typedef unsigned long long u64;

constexpr int TN = 64;
constexpr float W_INV = 1.1920928955078125e-7f;  // 2^-23

// ---------------- ws layout (26.25 MB) ----------------
// [0,16M)    XPk1: k-packed input bits u64 [2048 b][16 kb][64 t]  (ACC f32 aliases after K1)
// [16M,24M)  XP2 : k-packed s1 bits   u32 [2048 b][16 kw][64 t]
// [24M,...]  W1 digit tiles [3][4 hb][16 kb][128 row][64 k] i8 ; then W2 [3][4][8][128][64]
static constexpr size_t OFF_XP2 = (size_t)16 << 20;
static constexpr size_t OFF_W1  = (size_t)24 << 20;
static constexpr size_t OFF_W2  = OFF_W1 + ((size_t)3 * 4 * 16 * 8192);
static constexpr size_t WS_NEED = OFF_W2 + ((size_t)3 * 4 * 8 * 8192);

// ---------------- P0: bit-transpose-pack X  -> XP[b][kb][t] (u64) ----------------
__global__ __launch_bounds__(256) void pack_x(const float* __restrict__ X,
                                              u64* __restrict__ XP) {
    __shared__ float L[64 * 65];
    const int kw = blockIdx.x;   // 0..15 (kb)
    const int b  = blockIdx.y;   // 0..2047
    const int tid = threadIdx.x;
    const float* src = X + (((size_t)b * 1024 + kw * 64) << 6);
#pragma unroll
    for (int i = 0; i < 4; ++i) {
        int flat = tid + i * 256;
        float4 v = ((const float4*)src)[flat];
        int e0 = flat * 4;
        int k = e0 >> 6, t0 = e0 & 63;
        float* d = &L[k * 65 + t0];
        d[0] = v.x; d[1] = v.y; d[2] = v.z; d[3] = v.w;
    }
    __syncthreads();
    const int w = tid >> 6, lane = tid & 63;
    u64 myw = 0;
#pragma unroll
    for (int tt = 0; tt < 16; ++tt) {
        int t = w * 16 + tt;
        bool pred = L[lane * 65 + t] > 0.5f;   // lane indexes k
        u64 bm = __ballot(pred);
        if (lane == tt) myw = bm;
    }
    if (lane < 16) XP[((size_t)b * 16 + kw) * 64 + w * 16 + lane] = myw;
}

// ---------------- P1: quantize W (scale 2^23), 3-digit balanced base-128 split ----------------
// layout: [comp][hb][kb][row 0..127][k 0..63] i8
__global__ __launch_bounds__(256) void pack_w3(const float* __restrict__ W, int kshift, int KB,
                                               char* __restrict__ dAll) {
    int g = blockIdx.x * 256 + threadIdx.x;
    int h = g >> kshift;
    int k = g & ((1 << kshift) - 1);
    float v = W[g];
    int q  = (int)rintf(v * 8388608.f);       // |q| <= 370728
    int lo = ((q + 64) & 127) - 64;
    int q1 = (q - lo) >> 7;
    int mid = ((q1 + 64) & 127) - 64;
    int hi  = (q1 - mid) >> 7;                // |hi| <= 23
    size_t tile0 = (size_t)((h >> 7) * KB + (k >> 6)) * 8192;
    size_t inT   = (size_t)(h & 127) * 64 + (k & 63);
    size_t compStride = (size_t)4 * KB * 8192;
    dAll[tile0 + inT]                  = (char)hi;
    dAll[compStride + tile0 + inT]     = (char)mid;
    dAll[2 * compStride + tile0 + inT] = (char)lo;
}

// ---------------- main fused i8-MFMA GEMM + LIF scan (digit-folded waves) ----------------
// 256 thr = 4 waves = wm(2: 32h strip) x wn(2: which b). Block = 64h x 128n, grid (1024, 8).
// Wave: 32h x 64n x 3 digits in-register. Barrier-free K-loop; in-register digit combine;
// per-wave LDS slab only for the t-scan transpose.
// EMIT (K1): XPsrc = u64 [b][KB][64 t]; XPdst = u32 [b][16 kw][64 t].
// !EMIT (K2): XPsrc = u32 [b][16 kw][64 t]; AccOut f32 [b][512].
template <int KB, bool EMIT>
__global__ __launch_bounds__(256, 2) void spike_mfma_v3(
    const char* __restrict__ dAll,   // [3][4][KB][8192]
    const void* __restrict__ XPsrc,
    const float* __restrict__ bias,  // [512]
    uint* __restrict__ XPdst,
    float* __restrict__ AccOut)
{
    using BT = typename std::conditional<EMIT, u64, uint>::type;
    __shared__ float LS[4][32 * 35];
    const int tid = threadIdx.x;
    const int nb = blockIdx.x;    // 0..1023
    const int hy = blockIdx.y;    // 0..7 (64-row blocks)
    const int b0 = nb * 2;
    const int w = tid >> 6, lane = tid & 63;
    const int wm = w >> 1, wn = w & 1;
    const int l15 = lane & 15, lg = lane >> 4;
    const int bsel = b0 + wn;

    i32x4 acc[2][3][4] = {};   // [mi][digit][ni]

    // A: per-lane direct global load, fragment order. row = (hy&1)*64 + wm*32 + mi*16 + l15
    const char* aB[3];
#pragma unroll
    for (int d = 0; d < 3; ++d)
        aB[d] = dAll + ((size_t)(d * 4 + (hy >> 1)) * KB) * 8192
                + ((hy & 1) * 64 + wm * 32 + l15) * 64 + lg * 16;

    // B: spike words, one per (ni) per kb
    const BT* bp;
    uint shf;
    if constexpr (EMIT) {
        bp = (const BT*)XPsrc + (size_t)bsel * KB * 64 + l15;   // + kb*64 + ni*16
        shf = lg * 16;
    } else {
        bp = (const BT*)XPsrc + (size_t)bsel * 1024 + (lg >> 1) * 64 + l15;  // + kb*128 + ni*16
        shf = (lg & 1) * 16;
    }
    constexpr int BSTRIDE = EMIT ? 64 : 128;

    uint4 aC[2][3], aN[2][3];
    BT bC[4], bN[4];
#pragma unroll
    for (int mi = 0; mi < 2; ++mi)
#pragma unroll
        for (int d = 0; d < 3; ++d)
            aC[mi][d] = *(const uint4*)(aB[d] + mi * 1024);
#pragma unroll
    for (int ni = 0; ni < 4; ++ni) bC[ni] = bp[ni * 16];

#pragma unroll 2
    for (int kb = 0; kb < KB; ++kb) {
        if (kb + 1 < KB) {   // prefetch next tile into regs (in flight during MFMA)
#pragma unroll
            for (int mi = 0; mi < 2; ++mi)
#pragma unroll
                for (int d = 0; d < 3; ++d)
                    aN[mi][d] = *(const uint4*)(aB[d] + (size_t)(kb + 1) * 8192 + mi * 1024);
#pragma unroll
            for (int ni = 0; ni < 4; ++ni)
                bN[ni] = bp[(size_t)(kb + 1) * BSTRIDE + ni * 16];
        }
        __builtin_amdgcn_s_setprio(1);
#pragma unroll
        for (int ni = 0; ni < 4; ++ni) {
            uint field = (uint)(bC[ni] >> shf) & 0xFFFFu;
            i32x4 bf;
            bf[0] = (int)((((field      ) & 15u) * 0x204081u) & 0x01010101u);
            bf[1] = (int)((((field >>  4) & 15u) * 0x204081u) & 0x01010101u);
            bf[2] = (int)((((field >>  8) & 15u) * 0x204081u) & 0x01010101u);
            bf[3] = (int)((((field >> 12) & 15u) * 0x204081u) & 0x01010101u);
#pragma unroll
            for (int mi = 0; mi < 2; ++mi)
#pragma unroll
                for (int d = 0; d < 3; ++d)
                    acc[mi][d][ni] = __builtin_amdgcn_mfma_i32_16x16x64_i8(
                        __builtin_bit_cast(i32x4, aC[mi][d]), bf, acc[mi][d][ni], 0, 0, 0);
        }
        __builtin_amdgcn_s_setprio(0);
#pragma unroll
        for (int mi = 0; mi < 2; ++mi)
#pragma unroll
            for (int d = 0; d < 3; ++d) aC[mi][d] = aN[mi][d];
#pragma unroll
        for (int ni = 0; ni < 4; ++ni) bC[ni] = bN[ni];
    }

    // ---- epilogue: in-register digit combine; per-wave LDS transpose; LIF scan ----
    float* myLS = LS[w];
    const float bb = bias[hy * 64 + wm * 32 + (lane & 31)];
    float v = 0.f, s = 0.f, asum = 0.f;
    uint owbase = 0;
    if constexpr (EMIT) owbase = ((uint)bsel * 16 + hy * 2 + wm) * 64;

#pragma unroll
    for (int p = 0; p < 2; ++p) {
        // stage t-half p: values at (t = ni*16+l15, h = wm*32 + mi*16 + lg*4 + r)
#pragma unroll
        for (int nq = 0; nq < 2; ++nq) {
            const int ni = p * 2 + nq;
            const int tl = nq * 16 + l15;
#pragma unroll
            for (int mi = 0; mi < 2; ++mi) {
                i32x4 comb = (acc[mi][0][ni] << 14) + (acc[mi][1][ni] << 7) + acc[mi][2][ni];
#pragma unroll
                for (int r = 0; r < 4; ++r)
                    myLS[tl * 35 + mi * 16 + lg * 4 + r] = (float)comb[r] * W_INV;
            }
        }
        asm volatile("s_waitcnt lgkmcnt(0)" ::: "memory");
        if (lane < 32) {   // lane = h within strip
            uint myw = 0;
            for (int tt = 0; tt < 32; ++tt) {
                float cc = myLS[tt * 35 + lane] + bb;
                v = v * (1.f - s) * 0.75f + cc;
                bool sp = v > 0.5f;
                s = sp ? 1.f : 0.f;
                if constexpr (EMIT) {
                    u64 bm = __ballot(sp);
                    if (lane == tt) myw = (uint)bm;
                } else {
                    asum += s;
                }
            }
            if constexpr (EMIT) XPdst[owbase + p * 32 + lane] = myw;
        }
    }
    if constexpr (!EMIT) {
        if (lane < 32)
            AccOut[(size_t)bsel * 512 + hy * 64 + wm * 32 + lane] = asum;
    }
}

// ---------------- K3: out = ACC @ Wout^T + bout (f32 VALU) ----------------
__global__ __launch_bounds__(256) void k3_gemm(
    const float* __restrict__ A, const float* __restrict__ Wo,
    const float* __restrict__ bq, float* __restrict__ C) {
    __shared__ float Al[64][33];
    __shared__ float Bl[32][65];
    const int n0 = blockIdx.x * 64;
    const int m0 = blockIdx.y * 64;
    const int tid = threadIdx.x;
    const int c0 = (tid & 15) * 4;
    const int r0 = (tid >> 4) * 4;
    float acc[4][4];
#pragma unroll
    for (int i = 0; i < 4; ++i)
#pragma unroll
        for (int j = 0; j < 4; ++j) acc[i][j] = 0.f;
    for (int k0 = 0; k0 < 512; k0 += 32) {
#pragma unroll
        for (int i = 0; i < 2; ++i) {
            int g = tid + 256 * i;
            int row = g >> 3, c4 = g & 7;
            float4 v = *(const float4*)(A + (size_t)(m0 + row) * 512 + k0 + c4 * 4);
            float* d = &Al[row][c4 * 4];
            d[0] = v.x; d[1] = v.y; d[2] = v.z; d[3] = v.w;
        }
#pragma unroll
        for (int i = 0; i < 2; ++i) {
            int g = tid + 256 * i;
            int row = g >> 3, c4 = g & 7;
            float4 v = *(const float4*)(Wo + (size_t)(n0 + row) * 512 + k0 + c4 * 4);
            Bl[c4 * 4 + 0][row] = v.x; Bl[c4 * 4 + 1][row] = v.y;
            Bl[c4 * 4 + 2][row] = v.z; Bl[c4 * 4 + 3][row] = v.w;
        }
        __syncthreads();
#pragma unroll 8
        for (int kk = 0; kk < 32; ++kk) {
            float a0 = Al[r0 + 0][kk], a1 = Al[r0 + 1][kk];
            float a2 = Al[r0 + 2][kk], a3 = Al[r0 + 3][kk];
            float b0 = Bl[kk][c0 + 0], b1 = Bl[kk][c0 + 1];
            float b2 = Bl[kk][c0 + 2], b3 = Bl[kk][c0 + 3];
            acc[0][0] = fmaf(a0, b0, acc[0][0]); acc[0][1] = fmaf(a0, b1, acc[0][1]);
            acc[0][2] = fmaf(a0, b2, acc[0][2]); acc[0][3] = fmaf(a0, b3, acc[0][3]);
            acc[1][0] = fmaf(a1, b0, acc[1][0]); acc[1][1] = fmaf(a1, b1, acc[1][1]);
            acc[1][2] = fmaf(a1, b2, acc[1][2]); acc[1][3] = fmaf(a1, b3, acc[1][3]);
            acc[2][0] = fmaf(a2, b0, acc[2][0]); acc[2][1] = fmaf(a2, b1, acc[2][1]);
            acc[2][2] = fmaf(a2, b2, acc[2][2]); acc[2][3] = fmaf(a2, b3, acc[2][3]);
            acc[3][0] = fmaf(a3, b0, acc[3][0]); acc[3][1] = fmaf(a3, b1, acc[3][1]);
            acc[3][2] = fmaf(a3, b2, acc[3][2]); acc[3][3] = fmaf(a3, b3, acc[3][3]);
        }
        __syncthreads();
    }
#pragma unroll
    for (int i = 0; i < 4; ++i) {
        float4 o = make_float4(acc[i][0] + bq[n0 + c0 + 0], acc[i][1] + bq[n0 + c0 + 1],
                               acc[i][2] + bq[n0 + c0 + 2], acc[i][3] + bq[n0 + c0 + 3]);
        *(float4*)&C[(size_t)(m0 + r0 + i) * 512 + n0 + c0] = o;
    }
}

// ---------------- fallback f32 path (ws too small) ----------------
template <int KDIM, bool PIN>
__global__ __launch_bounds__(256) void gemm_scan(
    const float* __restrict__ Xf, const u64* __restrict__ Xp,
    const float* __restrict__ W, const float* __restrict__ bias,
    u64* __restrict__ Sout, float* __restrict__ AccOut) {
    __shared__ union {
        struct { float Wt[32 * 260]; float Xc[32 * 64]; } s;
        float C[256 * 64];
    } lds;
    const int b = blockIdx.y;
    const int h0 = blockIdx.x * 256;
    const int tid = threadIdx.x;
    const int tc = tid & 3, tr = tid >> 2;
    const int t0 = tc * 16, r0 = tr * 4;
    float c[4][16];
#pragma unroll
    for (int i = 0; i < 4; ++i)
#pragma unroll
        for (int j = 0; j < 16; ++j) c[i][j] = 0.f;
    for (int k0 = 0; k0 < KDIM; k0 += 32) {
        if constexpr (!PIN) {
            const float4* xsrc = (const float4*)(Xf + ((size_t)b * KDIM + k0) * 64);
            float4* xdst = (float4*)lds.s.Xc;
            xdst[tid] = xsrc[tid];
            xdst[tid + 256] = xsrc[tid + 256];
        } else {
            const int row = tid >> 3;
            const int bofs = (tid & 7) * 8;
            u64 m = Xp[(size_t)b * KDIM + k0 + row];
            float* xd = &lds.s.Xc[row * 64 + bofs];
#pragma unroll
            for (int q = 0; q < 8; ++q) xd[q] = (float)((m >> (bofs + q)) & 1ull);
        }
#pragma unroll
        for (int i = 0; i < 8; ++i) {
            int g = tid + 256 * i;
            int row = g >> 3, c4 = g & 7;
            float4 w4 = *(const float4*)(W + (size_t)(h0 + row) * KDIM + k0 + c4 * 4);
            lds.s.Wt[(c4 * 4 + 0) * 260 + row] = w4.x;
            lds.s.Wt[(c4 * 4 + 1) * 260 + row] = w4.y;
            lds.s.Wt[(c4 * 4 + 2) * 260 + row] = w4.z;
            lds.s.Wt[(c4 * 4 + 3) * 260 + row] = w4.w;
        }
        __syncthreads();
#pragma unroll 4
        for (int kk = 0; kk < 32; ++kk) {
            float4 wv = *(const float4*)&lds.s.Wt[kk * 260 + r0];
            const float4* xr = (const float4*)&lds.s.Xc[kk * 64 + t0];
            float4 x0 = xr[0], x1 = xr[1], x2 = xr[2], x3 = xr[3];
            float wr[4] = {wv.x, wv.y, wv.z, wv.w};
            float xs[16] = {x0.x, x0.y, x0.z, x0.w, x1.x, x1.y, x1.z, x1.w,
                            x2.x, x2.y, x2.z, x2.w, x3.x, x3.y, x3.z, x3.w};
#pragma unroll
            for (int i = 0; i < 4; ++i)
#pragma unroll
                for (int j = 0; j < 16; ++j) c[i][j] = fmaf(wr[i], xs[j], c[i][j]);
        }
        __syncthreads();
    }
#pragma unroll
    for (int i = 0; i < 4; ++i)
#pragma unroll
        for (int j4 = 0; j4 < 4; ++j4)
            *(float4*)&lds.C[(r0 + i) * 64 + t0 + j4 * 4] =
                make_float4(c[i][j4 * 4], c[i][j4 * 4 + 1], c[i][j4 * 4 + 2], c[i][j4 * 4 + 3]);
    __syncthreads();
    const float bb = bias[h0 + tid];
    float v = 0.f, s = 0.f;
    if constexpr (!PIN) {
        u64 m = 0;
#pragma unroll
        for (int t = 0; t < TN; ++t) {
            float cc = lds.C[tid * 64 + t] + bb;
            v = v * (1.f - s) * 0.75f + cc;
            bool sp = v > 0.5f;
            s = sp ? 1.f : 0.f;
            if (sp) m |= (1ull << t);
        }
        Sout[(size_t)b * 512 + h0 + tid] = m;
    } else {
        float acc = 0.f;
#pragma unroll
        for (int t = 0; t < TN; ++t) {
            float cc = lds.C[tid * 64 + t] + bb;
            v = v * (1.f - s) * 0.75f + cc;
            bool sp = v > 0.5f;
            s = sp ? 1.f : 0.f;
            acc += s;
        }
        AccOut[(size_t)b * 512 + h0 + tid] = acc;
    }
}

extern "C" void kernel_launch(void* const* d_in, const int* in_sizes, int n_in,
                              void* d_out, int out_size, void* d_ws, size_t ws_size,
                              hipStream_t stream) {
    const float* X  = (const float*)d_in[0];
    const float* W1 = (const float*)d_in[1];
    const float* b1 = (const float*)d_in[2];
    const float* W2 = (const float*)d_in[3];
    const float* b2 = (const float*)d_in[4];
    const float* Wo = (const float*)d_in[5];
    const float* bo = (const float*)d_in[6];
    float* out = (float*)d_out;

    if (ws_size >= WS_NEED) {
        char* ws = (char*)d_ws;
        u64* XPk1 = (u64*)ws;
        uint* XP2 = (uint*)(ws + OFF_XP2);
        char* W1d = ws + OFF_W1;
        char* W2d = ws + OFF_W2;
        float* ACC = (float*)ws;  // aliases XPk1 (dead after K1)

        pack_x<<<dim3(16, 2048), 256, 0, stream>>>(X, XPk1);
        pack_w3<<<dim3(2048), 256, 0, stream>>>(W1, 10, 16, W1d);
        pack_w3<<<dim3(1024), 256, 0, stream>>>(W2, 9, 8, W2d);
        spike_mfma_v3<16, true><<<dim3(1024, 8), 256, 0, stream>>>(W1d, XPk1, b1, XP2, nullptr);
        spike_mfma_v3<8, false><<<dim3(1024, 8), 256, 0, stream>>>(W2d, XP2, b2, nullptr, ACC);
        k3_gemm<<<dim3(8, 32), 256, 0, stream>>>(ACC, Wo, bo, out);
    } else {
        u64* S1 = (u64*)d_ws;
        float* ACC = (float*)((char*)d_ws + (size_t)2048 * 512 * 8);
        gemm_scan<1024, false><<<dim3(2, 2048), 256, 0, stream>>>(X, nullptr, W1, b1, S1, nullptr);
        gemm_scan<512, true><<<dim3(2, 2048), 256, 0, stream>>>(nullptr, S1, W2, b2, nullptr, ACC);
        k3_gemm<<<dim3(8, 32), 256, 0, stream>>>(ACC, Wo, bo, out);
    }
}

// Round 9
// 450.286 us; speedup vs baseline: 1.6438x; 1.1203x over previous
//
#include <hip/hip_runtime.h>
#include <hip/hip_bf16.h>
#include <type_traits>

typedef int  i32x4  __attribute__((ext_vector_type(4)));
typedef int  i32x16 __attribute__((ext_vector_type(16)));
typedef unsigned int uint;
typedef unsigned long long u64;

constexpr int TN = 64;
constexpr float W_INV  = 1.1920928955078125e-7f;   // 2^-23 (W1/W2 scale)
constexpr float WO_INV = 5.9604644775390625e-8f;   // 2^-24 (Wout scale)

// ---------------- ws layout (~27 MB) ----------------
// [0,16M)   XPk1 u64 [2048 b][16 kb][64 t]   (ACCb i8 [2048][512] aliases after K1)
// [16M,24M) XP2  u32 [2048 b][16 kw][64 t]
// [24M,+1.5M)   W1 digits [3][4 hb][16 kb][128 row][64 k] i8
// [+0.75M]      W2 digits [3][4][8][128][64] i8
// [+0.75M]      Wout digits [3][512 o][512 h] i8
static constexpr size_t OFF_XP2 = (size_t)16 << 20;
static constexpr size_t OFF_W1  = (size_t)24 << 20;
static constexpr size_t OFF_W2  = OFF_W1 + (size_t)3 * 4 * 16 * 8192;
static constexpr size_t OFF_WO  = OFF_W2 + (size_t)3 * 4 * 8 * 8192;
static constexpr size_t WS_NEED = OFF_WO + (size_t)3 * 512 * 512;

// ---------------- P0: bit-transpose-pack X  -> XP[b][kb][t] (u64) ----------------
__global__ __launch_bounds__(256) void pack_x(const float* __restrict__ X,
                                              u64* __restrict__ XP) {
    __shared__ float L[64 * 65];
    const int kw = blockIdx.x;   // 0..15 (kb)
    const int b  = blockIdx.y;   // 0..2047
    const int tid = threadIdx.x;
    const float* src = X + (((size_t)b * 1024 + kw * 64) << 6);
#pragma unroll
    for (int i = 0; i < 4; ++i) {
        int flat = tid + i * 256;
        float4 v = ((const float4*)src)[flat];
        int e0 = flat * 4;
        int k = e0 >> 6, t0 = e0 & 63;
        float* d = &L[k * 65 + t0];
        d[0] = v.x; d[1] = v.y; d[2] = v.z; d[3] = v.w;
    }
    __syncthreads();
    const int w = tid >> 6, lane = tid & 63;
    u64 myw = 0;
#pragma unroll
    for (int tt = 0; tt < 16; ++tt) {
        int t = w * 16 + tt;
        bool pred = L[lane * 65 + t] > 0.5f;   // lane indexes k
        u64 bm = __ballot(pred);
        if (lane == tt) myw = bm;
    }
    if (lane < 16) XP[((size_t)b * 16 + kw) * 64 + w * 16 + lane] = myw;
}

// ---------------- P1: quantize W (scale 2^23), 3-digit balanced base-128 ----------------
// layout: [comp][hb][kb][row 0..127][k 0..63] i8
__global__ __launch_bounds__(256) void pack_w3(const float* __restrict__ W, int kshift, int KB,
                                               char* __restrict__ dAll) {
    int g = blockIdx.x * 256 + threadIdx.x;
    int h = g >> kshift;
    int k = g & ((1 << kshift) - 1);
    float v = W[g];
    int q  = (int)rintf(v * 8388608.f);
    int lo = ((q + 64) & 127) - 64;
    int q1 = (q - lo) >> 7;
    int mid = ((q1 + 64) & 127) - 64;
    int hi  = (q1 - mid) >> 7;
    size_t tile0 = (size_t)((h >> 7) * KB + (k >> 6)) * 8192;
    size_t inT   = (size_t)(h & 127) * 64 + (k & 63);
    size_t compStride = (size_t)4 * KB * 8192;
    dAll[tile0 + inT]                  = (char)hi;
    dAll[compStride + tile0 + inT]     = (char)mid;
    dAll[2 * compStride + tile0 + inT] = (char)lo;
}

// ---------------- P2: quantize Wout (scale 2^24), 3-digit, plain [d][o][h] ----------------
__global__ __launch_bounds__(256) void pack_wout3(const float* __restrict__ W,
                                                  char* __restrict__ dAll) {
    int g = blockIdx.x * 256 + threadIdx.x;   // 262144 = 512*512
    float v = W[g];
    int q  = (int)rintf(v * 16777216.f);      // |q| <= ~742k; hi digit <= 46
    int lo = ((q + 64) & 127) - 64;
    int q1 = (q - lo) >> 7;
    int mid = ((q1 + 64) & 127) - 64;
    int hi  = (q1 - mid) >> 7;
    dAll[g]          = (char)hi;
    dAll[262144 + g] = (char)mid;
    dAll[524288 + g] = (char)lo;
}

// ---------------- main fused i8 32x32 MFMA GEMM + LIF scan ----------------
// 256 thr = 4 waves = wm(2: 32h strip) x wn(2: batch). Block 64h x 128n, grid (1024, 8).
// Wave: 32h x 64n x 3 digits, acc[3][2] i32x16. Barrier-free K-loop, reg digit-combine,
// per-wave LDS slab for the t-scan transpose.
template <int KB, bool EMIT>
__global__ __launch_bounds__(256, 2) void spike_mfma_v4(
    const char* __restrict__ dAll,   // [3][4][KB][8192]
    const void* __restrict__ XPsrc,
    const float* __restrict__ bias,  // [512]
    uint* __restrict__ XPdst,        // EMIT: u32 [b][16 kw][64 t]
    char* __restrict__ AccOut)       // !EMIT: i8 [b][512]
{
    __shared__ float LS[4][64 * 33];
    const int tid = threadIdx.x;
    const int nb = blockIdx.x, hy = blockIdx.y;
    const int b0 = nb * 2;
    const int w = tid >> 6, lane = tid & 63;
    const int wm = w >> 1, wn = w & 1;
    const int l31 = lane & 31, lh = lane >> 5;
    const int bsel = b0 + wn;

    i32x16 acc[3][2] = {};   // [digit][ni]

    const char* aBase = dAll + (size_t)(hy >> 1) * KB * 8192
                        + ((hy & 1) * 64 + wm * 32 + l31) * 64 + lh * 16;
    const size_t dStride = (size_t)4 * KB * 8192;

    const u64*  xp64 = (const u64*)XPsrc  + (size_t)bsel * KB * 64 + l31;
    const uint* xp32 = (const uint*)XPsrc + (size_t)bsel * 1024 + l31;

    uint4 aC[3][2], aN[3][2];
    u64  b64C[2] = {}, b64N[2] = {};
    uint b32C[4] = {}, b32N[4] = {};

    auto loadA = [&](int kb, uint4 (&dst)[3][2]) {
#pragma unroll
        for (int d = 0; d < 3; ++d)
#pragma unroll
            for (int ks = 0; ks < 2; ++ks)
                dst[d][ks] = *(const uint4*)(aBase + d * dStride + (size_t)kb * 8192 + ks * 32);
    };
    auto loadB = [&](int kb, u64 (&d64)[2], uint (&d32)[4]) {
        if constexpr (EMIT) {
#pragma unroll
            for (int ni = 0; ni < 2; ++ni)
                d64[ni] = xp64[(size_t)kb * 64 + ni * 32];
        } else {
#pragma unroll
            for (int ni = 0; ni < 2; ++ni)
#pragma unroll
                for (int ks = 0; ks < 2; ++ks)
                    d32[ni * 2 + ks] = xp32[(size_t)(kb * 2 + ks) * 64 + ni * 32];
        }
    };

    loadA(0, aC);
    loadB(0, b64C, b32C);

#pragma unroll 2
    for (int kb = 0; kb < KB; ++kb) {
        const int kbn = (kb + 1 < KB) ? kb + 1 : KB - 1;
        loadA(kbn, aN);
        loadB(kbn, b64N, b32N);
        __builtin_amdgcn_s_setprio(1);
#pragma unroll
        for (int ni = 0; ni < 2; ++ni)
#pragma unroll
            for (int ks = 0; ks < 2; ++ks) {
                uint f;
                if constexpr (EMIT)
                    f = (uint)(b64C[ni] >> (ks * 32 + lh * 16)) & 0xFFFFu;
                else
                    f = (b32C[ni * 2 + ks] >> (lh * 16)) & 0xFFFFu;
                i32x4 bf;
                bf[0] = (int)((((f      ) & 15u) * 0x204081u) & 0x01010101u);
                bf[1] = (int)((((f >>  4) & 15u) * 0x204081u) & 0x01010101u);
                bf[2] = (int)((((f >>  8) & 15u) * 0x204081u) & 0x01010101u);
                bf[3] = (int)((((f >> 12) & 15u) * 0x204081u) & 0x01010101u);
#pragma unroll
                for (int d = 0; d < 3; ++d)
                    acc[d][ni] = __builtin_amdgcn_mfma_i32_32x32x32_i8(
                        __builtin_bit_cast(i32x4, aC[d][ks]), bf, acc[d][ni], 0, 0, 0);
            }
        __builtin_amdgcn_s_setprio(0);
#pragma unroll
        for (int d = 0; d < 3; ++d) { aC[d][0] = aN[d][0]; aC[d][1] = aN[d][1]; }
        b64C[0] = b64N[0]; b64C[1] = b64N[1];
        b32C[0] = b32N[0]; b32C[1] = b32N[1]; b32C[2] = b32N[2]; b32C[3] = b32N[3];
    }

    // ---- epilogue: digit combine in reg; stage [t][h] (stride 33, conflict-free); scan ----
    float* myLS = LS[w];
#pragma unroll
    for (int ni = 0; ni < 2; ++ni) {
        const int t = ni * 32 + l31;
#pragma unroll
        for (int q = 0; q < 4; ++q)
#pragma unroll
            for (int j = 0; j < 4; ++j) {
                int r = q * 4 + j;
                int comb = (acc[0][ni][r] << 14) + (acc[1][ni][r] << 7) + acc[2][ni][r];
                myLS[t * 33 + q * 8 + lh * 4 + j] = (float)comb * W_INV;
            }
    }
    asm volatile("s_waitcnt lgkmcnt(0)" ::: "memory");
    __builtin_amdgcn_sched_barrier(0);
    if (lane < 32) {
        const float bb = bias[hy * 64 + wm * 32 + lane];
        float v = 0.f, s = 0.f;
        uint w0 = 0, w1 = 0;
        int asum = 0;
        for (int tt = 0; tt < TN; ++tt) {
            float cc = myLS[tt * 33 + lane] + bb;
            v = v * (1.f - s) * 0.75f + cc;
            bool sp = v > 0.5f;
            s = sp ? 1.f : 0.f;
            if constexpr (EMIT) {
                u64 bm = __ballot(sp);   // lanes >=32 masked off -> high bits 0
                if (lane == (tt & 31)) { if (tt < 32) w0 = (uint)bm; else w1 = (uint)bm; }
            } else {
                asum += sp ? 1 : 0;
            }
        }
        if constexpr (EMIT) {
            uint base = ((uint)bsel * 16 + hy * 2 + wm) * 64;
            XPdst[base + lane] = w0;
            XPdst[base + 32 + lane] = w1;
        } else {
            AccOut[(size_t)bsel * 512 + hy * 64 + wm * 32 + lane] = (char)asum;
        }
    }
}

// ---------------- K3: out = ACC @ Wout^T + bout via i8 MFMA ----------------
// grid (32 b-blocks, 4 o-blocks), 256 thr = 4 waves (o strips). Wave: 32o x 64b, K=512.
__global__ __launch_bounds__(256) void k3_i8(
    const char* __restrict__ dW,    // [3][512 o][512 h]
    const char* __restrict__ ACCb,  // [2048][512] i8
    const float* __restrict__ bq,   // [512]
    float* __restrict__ out)        // [2048][512]
{
    const int tid = threadIdx.x;
    const int w = tid >> 6, lane = tid & 63;
    const int l31 = lane & 31, lh = lane >> 5;
    const int bBlk = blockIdx.x * 64;
    const int oBase = blockIdx.y * 128 + w * 32;

    i32x16 acc[2][3] = {};   // [bi][digit]
    const char* aP = dW + (size_t)(oBase + l31) * 512 + lh * 16;
    const char* bP = ACCb + (size_t)(bBlk + l31) * 512 + lh * 16;

#pragma unroll 4
    for (int ks = 0; ks < 16; ++ks) {
        i32x4 af[3], bf[2];
#pragma unroll
        for (int d = 0; d < 3; ++d)
            af[d] = *(const i32x4*)(aP + (size_t)d * 262144 + ks * 32);
#pragma unroll
        for (int bi = 0; bi < 2; ++bi)
            bf[bi] = *(const i32x4*)(bP + (size_t)bi * 32 * 512 + ks * 32);
#pragma unroll
        for (int bi = 0; bi < 2; ++bi)
#pragma unroll
            for (int d = 0; d < 3; ++d)
                acc[bi][d] = __builtin_amdgcn_mfma_i32_32x32x32_i8(af[d], bf[bi], acc[bi][d], 0, 0, 0);
    }
#pragma unroll
    for (int bi = 0; bi < 2; ++bi) {
        const size_t b = bBlk + bi * 32 + l31;
#pragma unroll
        for (int q = 0; q < 4; ++q) {
            const int oo = oBase + q * 8 + lh * 4;
            float4 bb = *(const float4*)&bq[oo];
            float4 o4;
#pragma unroll
            for (int j = 0; j < 4; ++j) {
                int r = q * 4 + j;
                float dv = (float)acc[bi][0][r] * 16384.f
                         + (float)acc[bi][1][r] * 128.f
                         + (float)acc[bi][2][r];
                ((float*)&o4)[j] = dv * WO_INV + ((const float*)&bb)[j];
            }
            *(float4*)&out[b * 512 + oo] = o4;
        }
    }
}

// ---------------- fallback f32 path (ws too small) ----------------
template <int KDIM, bool PIN>
__global__ __launch_bounds__(256) void gemm_scan(
    const float* __restrict__ Xf, const u64* __restrict__ Xp,
    const float* __restrict__ W, const float* __restrict__ bias,
    u64* __restrict__ Sout, float* __restrict__ AccOut) {
    __shared__ union {
        struct { float Wt[32 * 260]; float Xc[32 * 64]; } s;
        float C[256 * 64];
    } lds;
    const int b = blockIdx.y;
    const int h0 = blockIdx.x * 256;
    const int tid = threadIdx.x;
    const int tc = tid & 3, tr = tid >> 2;
    const int t0 = tc * 16, r0 = tr * 4;
    float c[4][16];
#pragma unroll
    for (int i = 0; i < 4; ++i)
#pragma unroll
        for (int j = 0; j < 16; ++j) c[i][j] = 0.f;
    for (int k0 = 0; k0 < KDIM; k0 += 32) {
        if constexpr (!PIN) {
            const float4* xsrc = (const float4*)(Xf + ((size_t)b * KDIM + k0) * 64);
            float4* xdst = (float4*)lds.s.Xc;
            xdst[tid] = xsrc[tid];
            xdst[tid + 256] = xsrc[tid + 256];
        } else {
            const int row = tid >> 3;
            const int bofs = (tid & 7) * 8;
            u64 m = Xp[(size_t)b * KDIM + k0 + row];
            float* xd = &lds.s.Xc[row * 64 + bofs];
#pragma unroll
            for (int q = 0; q < 8; ++q) xd[q] = (float)((m >> (bofs + q)) & 1ull);
        }
#pragma unroll
        for (int i = 0; i < 8; ++i) {
            int g = tid + 256 * i;
            int row = g >> 3, c4 = g & 7;
            float4 w4 = *(const float4*)(W + (size_t)(h0 + row) * KDIM + k0 + c4 * 4);
            lds.s.Wt[(c4 * 4 + 0) * 260 + row] = w4.x;
            lds.s.Wt[(c4 * 4 + 1) * 260 + row] = w4.y;
            lds.s.Wt[(c4 * 4 + 2) * 260 + row] = w4.z;
            lds.s.Wt[(c4 * 4 + 3) * 260 + row] = w4.w;
        }
        __syncthreads();
#pragma unroll 4
        for (int kk = 0; kk < 32; ++kk) {
            float4 wv = *(const float4*)&lds.s.Wt[kk * 260 + r0];
            const float4* xr = (const float4*)&lds.s.Xc[kk * 64 + t0];
            float4 x0 = xr[0], x1 = xr[1], x2 = xr[2], x3 = xr[3];
            float wr[4] = {wv.x, wv.y, wv.z, wv.w};
            float xs[16] = {x0.x, x0.y, x0.z, x0.w, x1.x, x1.y, x1.z, x1.w,
                            x2.x, x2.y, x2.z, x2.w, x3.x, x3.y, x3.z, x3.w};
#pragma unroll
            for (int i = 0; i < 4; ++i)
#pragma unroll
                for (int j = 0; j < 16; ++j) c[i][j] = fmaf(wr[i], xs[j], c[i][j]);
        }
        __syncthreads();
    }
#pragma unroll
    for (int i = 0; i < 4; ++i)
#pragma unroll
        for (int j4 = 0; j4 < 4; ++j4)
            *(float4*)&lds.C[(r0 + i) * 64 + t0 + j4 * 4] =
                make_float4(c[i][j4 * 4], c[i][j4 * 4 + 1], c[i][j4 * 4 + 2], c[i][j4 * 4 + 3]);
    __syncthreads();
    const float bb = bias[h0 + tid];
    float v = 0.f, s = 0.f;
    if constexpr (!PIN) {
        u64 m = 0;
#pragma unroll
        for (int t = 0; t < TN; ++t) {
            float cc = lds.C[tid * 64 + t] + bb;
            v = v * (1.f - s) * 0.75f + cc;
            bool sp = v > 0.5f;
            s = sp ? 1.f : 0.f;
            if (sp) m |= (1ull << t);
        }
        Sout[(size_t)b * 512 + h0 + tid] = m;
    } else {
        float acc = 0.f;
#pragma unroll
        for (int t = 0; t < TN; ++t) {
            float cc = lds.C[tid * 64 + t] + bb;
            v = v * (1.f - s) * 0.75f + cc;
            bool sp = v > 0.5f;
            s = sp ? 1.f : 0.f;
            acc += s;
        }
        AccOut[(size_t)b * 512 + h0 + tid] = acc;
    }
}

__global__ __launch_bounds__(256) void k3_f32(
    const float* __restrict__ A, const float* __restrict__ Wo,
    const float* __restrict__ bq, float* __restrict__ C) {
    __shared__ float Al[64][33];
    __shared__ float Bl[32][65];
    const int n0 = blockIdx.x * 64;
    const int m0 = blockIdx.y * 64;
    const int tid = threadIdx.x;
    const int c0 = (tid & 15) * 4;
    const int r0 = (tid >> 4) * 4;
    float acc[4][4];
#pragma unroll
    for (int i = 0; i < 4; ++i)
#pragma unroll
        for (int j = 0; j < 4; ++j) acc[i][j] = 0.f;
    for (int k0 = 0; k0 < 512; k0 += 32) {
#pragma unroll
        for (int i = 0; i < 2; ++i) {
            int g = tid + 256 * i;
            int row = g >> 3, c4 = g & 7;
            float4 v = *(const float4*)(A + (size_t)(m0 + row) * 512 + k0 + c4 * 4);
            float* d = &Al[row][c4 * 4];
            d[0] = v.x; d[1] = v.y; d[2] = v.z; d[3] = v.w;
        }
#pragma unroll
        for (int i = 0; i < 2; ++i) {
            int g = tid + 256 * i;
            int row = g >> 3, c4 = g & 7;
            float4 v = *(const float4*)(Wo + (size_t)(n0 + row) * 512 + k0 + c4 * 4);
            Bl[c4 * 4 + 0][row] = v.x; Bl[c4 * 4 + 1][row] = v.y;
            Bl[c4 * 4 + 2][row] = v.z; Bl[c4 * 4 + 3][row] = v.w;
        }
        __syncthreads();
#pragma unroll 8
        for (int kk = 0; kk < 32; ++kk) {
            float a0 = Al[r0 + 0][kk], a1 = Al[r0 + 1][kk];
            float a2 = Al[r0 + 2][kk], a3 = Al[r0 + 3][kk];
            float b0 = Bl[kk][c0 + 0], b1 = Bl[kk][c0 + 1];
            float b2 = Bl[kk][c0 + 2], b3 = Bl[kk][c0 + 3];
            acc[0][0] = fmaf(a0, b0, acc[0][0]); acc[0][1] = fmaf(a0, b1, acc[0][1]);
            acc[0][2] = fmaf(a0, b2, acc[0][2]); acc[0][3] = fmaf(a0, b3, acc[0][3]);
            acc[1][0] = fmaf(a1, b0, acc[1][0]); acc[1][1] = fmaf(a1, b1, acc[1][1]);
            acc[1][2] = fmaf(a1, b2, acc[1][2]); acc[1][3] = fmaf(a1, b3, acc[1][3]);
            acc[2][0] = fmaf(a2, b0, acc[2][0]); acc[2][1] = fmaf(a2, b1, acc[2][1]);
            acc[2][2] = fmaf(a2, b2, acc[2][2]); acc[2][3] = fmaf(a2, b3, acc[2][3]);
            acc[3][0] = fmaf(a3, b0, acc[3][0]); acc[3][1] = fmaf(a3, b1, acc[3][1]);
            acc[3][2] = fmaf(a3, b2, acc[3][2]); acc[3][3] = fmaf(a3, b3, acc[3][3]);
        }
        __syncthreads();
    }
#pragma unroll
    for (int i = 0; i < 4; ++i) {
        float4 o = make_float4(acc[i][0] + bq[n0 + c0 + 0], acc[i][1] + bq[n0 + c0 + 1],
                               acc[i][2] + bq[n0 + c0 + 2], acc[i][3] + bq[n0 + c0 + 3]);
        *(float4*)&C[(size_t)(m0 + r0 + i) * 512 + n0 + c0] = o;
    }
}

extern "C" void kernel_launch(void* const* d_in, const int* in_sizes, int n_in,
                              void* d_out, int out_size, void* d_ws, size_t ws_size,
                              hipStream_t stream) {
    const float* X  = (const float*)d_in[0];
    const float* W1 = (const float*)d_in[1];
    const float* b1 = (const float*)d_in[2];
    const float* W2 = (const float*)d_in[3];
    const float* b2 = (const float*)d_in[4];
    const float* Wo = (const float*)d_in[5];
    const float* bo = (const float*)d_in[6];
    float* out = (float*)d_out;

    if (ws_size >= WS_NEED) {
        char* ws = (char*)d_ws;
        u64* XPk1 = (u64*)ws;
        uint* XP2 = (uint*)(ws + OFF_XP2);
        char* W1d = ws + OFF_W1;
        char* W2d = ws + OFF_W2;
        char* WoD = ws + OFF_WO;
        char* ACCb = ws;   // aliases XPk1 (dead after K1)

        pack_x<<<dim3(16, 2048), 256, 0, stream>>>(X, XPk1);
        pack_w3<<<dim3(2048), 256, 0, stream>>>(W1, 10, 16, W1d);
        pack_w3<<<dim3(1024), 256, 0, stream>>>(W2, 9, 8, W2d);
        pack_wout3<<<dim3(1024), 256, 0, stream>>>(Wo, WoD);
        spike_mfma_v4<16, true><<<dim3(1024, 8), 256, 0, stream>>>(W1d, XPk1, b1, XP2, nullptr);
        spike_mfma_v4<8, false><<<dim3(1024, 8), 256, 0, stream>>>(W2d, XP2, b2, nullptr, ACCb);
        k3_i8<<<dim3(32, 4), 256, 0, stream>>>(WoD, ACCb, bo, out);
    } else {
        u64* S1 = (u64*)d_ws;
        float* ACC = (float*)((char*)d_ws + (size_t)2048 * 512 * 8);
        gemm_scan<1024, false><<<dim3(2, 2048), 256, 0, stream>>>(X, nullptr, W1, b1, S1, nullptr);
        gemm_scan<512, true><<<dim3(2, 2048), 256, 0, stream>>>(nullptr, S1, W2, b2, nullptr, ACC);
        k3_f32<<<dim3(8, 32), 256, 0, stream>>>(ACC, Wo, bo, out);
    }
}